// Round 5
// baseline (682.509 us; speedup 1.0000x reference)
//
#include <hip/hip_runtime.h>

// HyperGAT layer, N=16384, E=4096, D=256 on gfx950.
//   xw1 = x@w1 (split-bf16 MFMA, ~fp32 accurate)
//   g_n = satexp(leaky(xw1)@a1), d_n = leaky(xw1)@a22
//   y = g*xw1 quantized to i16 (per-dd global scale), split qh/ql i8 planes
//   C1 = H^T @ [qh|ql]  (i8 MFMA, hi/lo folded: A-tile read once for both planes)
//   f2 = leaky(C1/den);  G = f2@w2 (split);  c_j = leaky(G)@a21
//   out = leaky((B@G)/rowsum) with B[n,j] = Hbit*satexp(c_j+d_n) computed
//   ON THE FLY inside the final GEMM (fused_out) -- Bmat never materialized.

typedef __attribute__((ext_vector_type(8))) short short8;
typedef __attribute__((ext_vector_type(4))) float f32x4;
typedef __attribute__((ext_vector_type(4))) int int4v;
typedef __attribute__((ext_vector_type(4))) unsigned int uint4v;

__device__ __forceinline__ float leakyf(float v) { return v > 0.f ? v : 0.1f * v; }
__device__ __forceinline__ float fastrcp(float x) { return __builtin_amdgcn_rcpf(x); }

// exp(8*tanh(t/8)), branchless, overflow-safe
__device__ __forceinline__ float satexpf(float t) {
    float u = fminf(fmaxf(t * 0.25f, -30.f), 30.f);
    float p = __expf(u);
    float th = (p - 1.f) * fastrcp(p + 1.f);
    return __expf(8.f * th);
}

__device__ __forceinline__ short f2b(float v) {
    unsigned int x = __float_as_uint(v);
    x += 0x7fffu + ((x >> 16) & 1u);
    return (short)(x >> 16);
}
__device__ __forceinline__ float b2f(short s) {
    return __uint_as_float(((unsigned int)(unsigned short)s) << 16);
}

// ---------------------------------------------------------------- weight transposes (w1,w2) + hi/lo split, one dispatch
__global__ __launch_bounds__(256) void transpose_split2(
        const float* __restrict__ s0, short* __restrict__ dh0, short* __restrict__ dl0,
        const float* __restrict__ s1, short* __restrict__ dh1, short* __restrict__ dl1) {
    const float* src = blockIdx.z ? s1 : s0;
    short* dh = blockIdx.z ? dh1 : dh0;
    short* dl = blockIdx.z ? dl1 : dl0;
    __shared__ float Ts[64][65];
    const int t = threadIdx.x;
    const long r0 = (long)blockIdx.x * 64;
    const long c0 = (long)blockIdx.y * 64;
    {
        const int row = t >> 2, cc = (t & 3) * 16;
        const float* p = src + (r0 + row) * 256 + c0 + cc;
#pragma unroll
        for (int i = 0; i < 4; ++i) {
            f32x4 v = *reinterpret_cast<const f32x4*>(p + i * 4);
#pragma unroll
            for (int k = 0; k < 4; ++k) Ts[row][cc + i * 4 + k] = v[k];
        }
    }
    __syncthreads();
    {
        const int cl = t >> 2, ch = (t & 3) * 16;
        short8 h0, h1, l0, l1;
#pragma unroll
        for (int i = 0; i < 8; ++i) {
            float v = Ts[ch + i][cl];
            short h = f2b(v);
            h0[i] = h; l0[i] = f2b(v - b2f(h));
        }
#pragma unroll
        for (int i = 0; i < 8; ++i) {
            float v = Ts[ch + 8 + i][cl];
            short h = f2b(v);
            h1[i] = h; l1[i] = f2b(v - b2f(h));
        }
        short* qh = dh + (c0 + cl) * 256 + r0 + ch;
        short* ql = dl + (c0 + cl) * 256 + r0 + ch;
        *reinterpret_cast<short8*>(qh) = h0;
        *reinterpret_cast<short8*>(qh + 8) = h1;
        *reinterpret_cast<short8*>(ql) = l0;
        *reinterpret_cast<short8*>(ql + 8) = l1;
    }
}

// ---------------------------------------------------------------- H: fp32 [16384,4096] -> HbT i8 [4096,16384] + Hbits u32 [16384,128]
__global__ __launch_bounds__(256) void transposeH_pack(
        const float* __restrict__ H, char* __restrict__ HbT,
        unsigned int* __restrict__ Hbits) {
    __shared__ float Ts[64][65];
    const int t = threadIdx.x;
    const long r0 = (long)blockIdx.x * 64;   // n
    const long c0 = (long)blockIdx.y * 64;   // j
    {
        const int row = t >> 2, cc = (t & 3) * 16;
        const float* p = H + (r0 + row) * 4096L + c0 + cc;
#pragma unroll
        for (int i = 0; i < 4; ++i) {
            f32x4 v = *reinterpret_cast<const f32x4*>(p + i * 4);
#pragma unroll
            for (int k = 0; k < 4; ++k) Ts[row][cc + i * 4 + k] = v[k];
        }
    }
    __syncthreads();
    {
        const int cl = t >> 2, ch = (t & 3) * 16;
        uint4v pk;
#pragma unroll
        for (int wv = 0; wv < 4; ++wv) {
            unsigned int u = 0;
#pragma unroll
            for (int b = 0; b < 4; ++b)
                u |= (Ts[ch + wv * 4 + b][cl] != 0.f ? 1u : 0u) << (8 * b);
            pk[wv] = u;
        }
        *reinterpret_cast<uint4v*>(HbT + (c0 + cl) * 16384L + r0 + ch) = pk;
    }
    if (t < 128) {
        const int nl = t >> 1, w = t & 1;
        unsigned int u = 0;
#pragma unroll
        for (int b = 0; b < 32; ++b)
            u |= (Ts[nl][w * 32 + b] != 0.f ? 1u : 0u) << b;
        Hbits[(r0 + nl) * 128 + (c0 >> 5) + w] = u;
    }
}

// ---------------------------------------------------------------- xw1 split GEMM (fp32-accurate)
__global__ __launch_bounds__(256) void gemm_xw1(
        const float* __restrict__ A, const short* __restrict__ Bh,
        const short* __restrict__ Bl, float* __restrict__ C) {
    __shared__ short Ash[128][72];
    __shared__ short Asl[128][72];
    __shared__ short Bsh[64][72];
    __shared__ short Bsl[64][72];
    const int t = threadIdx.x;
    const int wid = t >> 6, lane = t & 63;
    const int wm = wid & 1, wn = wid >> 1;
    const int quad = lane >> 4, l15 = lane & 15;
    const long m0 = (long)blockIdx.x * 128;
    const long n0 = (long)blockIdx.y * 64;
    f32x4 acc[4][2];
#pragma unroll
    for (int i = 0; i < 4; ++i)
#pragma unroll
        for (int j = 0; j < 2; ++j)
#pragma unroll
            for (int r = 0; r < 4; ++r) acc[i][j][r] = 0.f;

    for (int kb = 0; kb < 256; kb += 64) {
#pragma unroll
        for (int it = 0; it < 4; ++it) {
            const int cid = t + it * 256;
            const int row = cid >> 3, c8 = (cid & 7) * 8;
            const float* ap = A + (m0 + row) * 256 + kb + c8;
            f32x4 v0 = *reinterpret_cast<const f32x4*>(ap);
            f32x4 v1 = *reinterpret_cast<const f32x4*>(ap + 4);
            short8 hi, lo;
#pragma unroll
            for (int k = 0; k < 4; ++k) {
                short h0 = f2b(v0[k]); hi[k] = h0; lo[k] = f2b(v0[k] - b2f(h0));
                short h1 = f2b(v1[k]); hi[4 + k] = h1; lo[4 + k] = f2b(v1[k] - b2f(h1));
            }
            *reinterpret_cast<short8*>(&Ash[row][c8]) = hi;
            *reinterpret_cast<short8*>(&Asl[row][c8]) = lo;
        }
#pragma unroll
        for (int it = 0; it < 2; ++it) {
            const int cid = t + it * 256;
            const int row = cid >> 3, c8 = (cid & 7) * 8;
            *reinterpret_cast<short8*>(&Bsh[row][c8]) =
                *reinterpret_cast<const short8*>(Bh + (n0 + row) * 256 + kb + c8);
            *reinterpret_cast<short8*>(&Bsl[row][c8]) =
                *reinterpret_cast<const short8*>(Bl + (n0 + row) * 256 + kb + c8);
        }
        __syncthreads();
#pragma unroll
        for (int ks = 0; ks < 2; ++ks) {
            short8 ah[4], al[4], bh[2], bl[2];
#pragma unroll
            for (int i = 0; i < 4; ++i) {
                ah[i] = *reinterpret_cast<const short8*>(&Ash[wm * 64 + i * 16 + l15][ks * 32 + quad * 8]);
                al[i] = *reinterpret_cast<const short8*>(&Asl[wm * 64 + i * 16 + l15][ks * 32 + quad * 8]);
            }
#pragma unroll
            for (int j = 0; j < 2; ++j) {
                bh[j] = *reinterpret_cast<const short8*>(&Bsh[wn * 32 + j * 16 + l15][ks * 32 + quad * 8]);
                bl[j] = *reinterpret_cast<const short8*>(&Bsl[wn * 32 + j * 16 + l15][ks * 32 + quad * 8]);
            }
#pragma unroll
            for (int i = 0; i < 4; ++i)
#pragma unroll
                for (int j = 0; j < 2; ++j) {
                    acc[i][j] = __builtin_amdgcn_mfma_f32_16x16x32_bf16(ah[i], bh[j], acc[i][j], 0, 0, 0);
                    acc[i][j] = __builtin_amdgcn_mfma_f32_16x16x32_bf16(ah[i], bl[j], acc[i][j], 0, 0, 0);
                    acc[i][j] = __builtin_amdgcn_mfma_f32_16x16x32_bf16(al[i], bh[j], acc[i][j], 0, 0, 0);
                }
        }
        __syncthreads();
    }
#pragma unroll
    for (int i = 0; i < 4; ++i) {
        const long grow = m0 + wm * 64 + i * 16 + quad * 4;
#pragma unroll
        for (int j = 0; j < 2; ++j) {
            const long gcol = n0 + wn * 32 + j * 16 + l15;
#pragma unroll
            for (int r = 0; r < 4; ++r)
                C[(grow + r) * 256 + gcol] = acc[i][j][r];
        }
    }
}

// ---------------------------------------------------------------- node stats: g, dn, per-dd |y| max
__global__ __launch_bounds__(256) void node_stats1(
        const float* __restrict__ xw1, const float* __restrict__ a1,
        const float* __restrict__ a22, float* __restrict__ g_out,
        float* __restrict__ dn, unsigned int* __restrict__ ddmax) {
    __shared__ float Mx[4][260];
    const int t = threadIdx.x;
    const int n0 = blockIdx.x * 64;
    const int r = t >> 2, q = t & 3;
    const long n = n0 + r;
    const float* xp = xw1 + n * 256 + q * 64;
    float vals[64];
    float facc = 0.f, dacc = 0.f;
#pragma unroll
    for (int i = 0; i < 16; ++i) {
        f32x4 v  = *reinterpret_cast<const f32x4*>(xp + i * 4);
        f32x4 b1 = *reinterpret_cast<const f32x4*>(a1 + q * 64 + i * 4);
        f32x4 b2 = *reinterpret_cast<const f32x4*>(a22 + q * 64 + i * 4);
#pragma unroll
        for (int k = 0; k < 4; ++k) {
            float lv = leakyf(v[k]);
            facc += lv * b1[k];
            dacc += lv * b2[k];
            vals[i * 4 + k] = v[k];
        }
    }
    facc += __shfl_xor(facc, 1); facc += __shfl_xor(facc, 2);
    dacc += __shfl_xor(dacc, 1); dacc += __shfl_xor(dacc, 2);
    const float g = satexpf(facc);
    if (q == 0) { dn[n] = dacc; g_out[n] = g; }
    float lm[64];
#pragma unroll
    for (int i = 0; i < 64; ++i) lm[i] = fabsf(vals[i] * g);
#pragma unroll
    for (int m = 4; m < 64; m <<= 1)
#pragma unroll
        for (int i = 0; i < 64; ++i) lm[i] = fmaxf(lm[i], __shfl_xor(lm[i], m));
    float gm = g;
#pragma unroll
    for (int m = 1; m < 64; m <<= 1) gm = fmaxf(gm, __shfl_xor(gm, m));
    const int wv = t >> 6, lane = t & 63;
    if (lane < 4) {
#pragma unroll
        for (int i = 0; i < 64; ++i) Mx[wv][lane * 64 + i] = lm[i];
    }
    if (lane == 0) Mx[wv][256] = gm;
    __syncthreads();
    if (t < 256) {
        float m = fmaxf(fmaxf(Mx[0][t], Mx[1][t]), fmaxf(Mx[2][t], Mx[3][t]));
        atomicMax(&ddmax[t], __float_as_uint(m));
    }
    if (t == 0) {  // index 256 (g) -- block only has 256 threads
        float m = fmaxf(fmaxf(Mx[0][256], Mx[1][256]), fmaxf(Mx[2][256], Mx[3][256]));
        atomicMax(&ddmax[256], __float_as_uint(m));
    }
}

// ---------------------------------------------------------------- quantize y -> yQ i8 [576,16384] (hi rows 0..287, lo 288..575)
__global__ __launch_bounds__(256) void quantize_y(
        const float* __restrict__ xw1, const float* __restrict__ g_in,
        const unsigned int* __restrict__ ddmax, char* __restrict__ yQ) {
    __shared__ unsigned int Qh[257][16];
    __shared__ unsigned int Ql[257][16];
    const int t = threadIdx.x;
    const int n0 = blockIdx.x * 64;
    const int dd0 = (t >> 4) * 16;
    const int w = t & 15;
    const int r4 = w * 4;
    float s[16];
#pragma unroll
    for (int i = 0; i < 16; ++i)
        s[i] = 32512.f / __uint_as_float(ddmax[dd0 + i]);
    const float sg = 32512.f / __uint_as_float(ddmax[256]);
    unsigned int bh[16], bl[16];
#pragma unroll
    for (int i = 0; i < 16; ++i) { bh[i] = 0u; bl[i] = 0u; }
    unsigned int gh = 0u, gl = 0u;
#pragma unroll
    for (int rr = 0; rr < 4; ++rr) {
        const long n = n0 + r4 + rr;
        const float gg = g_in[n];
        const float* xp = xw1 + n * 256 + dd0;
#pragma unroll
        for (int c = 0; c < 4; ++c) {
            f32x4 v = *reinterpret_cast<const f32x4*>(xp + c * 4);
#pragma unroll
            for (int k = 0; k < 4; ++k) {
                const int i = c * 4 + k;
                int qv = __float2int_rn(v[k] * gg * s[i]);
                qv = max(-32639, min(32639, qv));
                const int qh = (qv + 128) >> 8;
                const int ql = qv - (qh << 8);
                bh[i] |= ((unsigned int)(qh & 255)) << (8 * rr);
                bl[i] |= ((unsigned int)(ql & 255)) << (8 * rr);
            }
        }
        if (t < 16) {
            int qv = __float2int_rn(gg * sg);
            qv = max(-32639, min(32639, qv));
            const int qh = (qv + 128) >> 8;
            const int ql = qv - (qh << 8);
            gh |= ((unsigned int)(qh & 255)) << (8 * rr);
            gl |= ((unsigned int)(ql & 255)) << (8 * rr);
        }
    }
#pragma unroll
    for (int i = 0; i < 16; ++i) { Qh[dd0 + i][w] = bh[i]; Ql[dd0 + i][w] = bl[i]; }
    if (t < 16) { Qh[256][t] = gh; Ql[256][t] = gl; }
    __syncthreads();
#pragma unroll
    for (int it = 0; it < 2; ++it) {
        const int dd = it * 256 + t;
        if (dd < 288) {
#pragma unroll
            for (int s2 = 0; s2 < 4; ++s2) {
                uint4v vh, vl;
                if (dd < 257) {
                    vh = *reinterpret_cast<const uint4v*>(&Qh[dd][s2 * 4]);
                    vl = *reinterpret_cast<const uint4v*>(&Ql[dd][s2 * 4]);
                } else {
#pragma unroll
                    for (int k = 0; k < 4; ++k) { vh[k] = 0u; vl[k] = 0u; }
                }
                *reinterpret_cast<uint4v*>(yQ + (long)dd * 16384 + n0 + s2 * 16) = vh;
                *reinterpret_cast<uint4v*>(yQ + (long)(288 + dd) * 16384 + n0 + s2 * 16) = vl;
            }
        }
    }
}

// ---------------------------------------------------------------- C1 GEMM, i8 MFMA 16x16x64, hi/lo FOLDED
// A = HbT i8 [4096,16384] read once per (m,n,z); B planes hi(rows dd) / lo(rows 288+dd).
// BM=128 (j), BN=96 (dd), BK=128, z=8 (Ktile 2048), grid (32, 3, 8).
// Epilogue combines 256*hi+lo into fp32 partials Cp [8][4096][288].
__global__ __launch_bounds__(256) void gemm_c1_i8(
        const char* __restrict__ Ab, const char* __restrict__ Bb,
        float* __restrict__ Cp) {
    __shared__ char As[128][144];
    __shared__ char Bsh[96][144];
    __shared__ char Bsl[96][144];
    const int t = threadIdx.x;
    const int wid = t >> 6, lane = t & 63;
    const int wm = wid & 1, wn = wid >> 1;
    const int quad = lane >> 4, l15 = lane & 15;
    const long m0 = (long)blockIdx.x * 128;
    const long n0 = (long)blockIdx.y * 96;
    const long k0 = (long)blockIdx.z * 2048;
    float* Cz = Cp + (long)blockIdx.z * (4096L * 288);
    int4v acch[4][3], accl[4][3];
#pragma unroll
    for (int i = 0; i < 4; ++i)
#pragma unroll
        for (int j = 0; j < 3; ++j)
#pragma unroll
            for (int r = 0; r < 4; ++r) { acch[i][j][r] = 0; accl[i][j][r] = 0; }

    for (int kb = 0; kb < 2048; kb += 128) {
#pragma unroll
        for (int it = 0; it < 4; ++it) {
            const int cid = t + it * 256;
            const int row = cid >> 3, seg = (cid & 7) * 16;
            *reinterpret_cast<uint4v*>(&As[row][seg]) =
                *reinterpret_cast<const uint4v*>(Ab + (m0 + row) * 16384 + k0 + kb + seg);
        }
#pragma unroll
        for (int it = 0; it < 3; ++it) {
            const int cid = t + it * 256;
            const int row = cid >> 3, seg = (cid & 7) * 16;
            *reinterpret_cast<uint4v*>(&Bsh[row][seg]) =
                *reinterpret_cast<const uint4v*>(Bb + (n0 + row) * 16384 + k0 + kb + seg);
            *reinterpret_cast<uint4v*>(&Bsl[row][seg]) =
                *reinterpret_cast<const uint4v*>(Bb + (288 + n0 + row) * 16384 + k0 + kb + seg);
        }
        __syncthreads();
#pragma unroll
        for (int ks = 0; ks < 2; ++ks) {
            int4v af[4], bh[3], bl[3];
#pragma unroll
            for (int i = 0; i < 4; ++i)
                af[i] = *reinterpret_cast<const int4v*>(
                        &As[wm * 64 + i * 16 + l15][ks * 64 + quad * 16]);
#pragma unroll
            for (int j = 0; j < 3; ++j) {
                bh[j] = *reinterpret_cast<const int4v*>(
                        &Bsh[wn * 48 + j * 16 + l15][ks * 64 + quad * 16]);
                bl[j] = *reinterpret_cast<const int4v*>(
                        &Bsl[wn * 48 + j * 16 + l15][ks * 64 + quad * 16]);
            }
#pragma unroll
            for (int i = 0; i < 4; ++i)
#pragma unroll
                for (int j = 0; j < 3; ++j) {
                    acch[i][j] = __builtin_amdgcn_mfma_i32_16x16x64_i8(af[i], bh[j], acch[i][j], 0, 0, 0);
                    accl[i][j] = __builtin_amdgcn_mfma_i32_16x16x64_i8(af[i], bl[j], accl[i][j], 0, 0, 0);
                }
        }
        __syncthreads();
    }
#pragma unroll
    for (int i = 0; i < 4; ++i) {
        const long grow = m0 + wm * 64 + i * 16 + quad * 4;
#pragma unroll
        for (int j = 0; j < 3; ++j) {
            const long gcol = n0 + wn * 48 + j * 16 + l15;
#pragma unroll
            for (int r = 0; r < 4; ++r)
                Cz[(grow + r) * 288 + gcol] =
                    256.f * (float)acch[i][j][r] + (float)accl[i][j][r];
        }
    }
}

// ---------------------------------------------------------------- reduce split-K partials + reconstruct scale
__global__ __launch_bounds__(256) void reduce_C1(
        const float* __restrict__ C1p, const unsigned int* __restrict__ ddmax,
        float* __restrict__ C1) {
    const int i = blockIdx.x * 256 + threadIdx.x;   // < 4096*288
    const int dd = i % 288;
    float s = 0.f;
#pragma unroll
    for (int z = 0; z < 8; ++z) s += C1p[(long)z * 4096 * 288 + i];
    C1[i] = s * (__uint_as_float(ddmax[dd]) * (1.f / 32512.f));
}

// ---------------------------------------------------------------- G = f2@w2 split (+ GT bf16, c_j)
__global__ __launch_bounds__(256) void gemm_G(
        const float* __restrict__ C1, const short* __restrict__ w2Th,
        const short* __restrict__ w2Tl, const float* __restrict__ a21,
        short* __restrict__ GT, float* __restrict__ cat) {
    __shared__ short Ash[64][72];
    __shared__ short Asl[64][72];
    __shared__ short Bsh[64][72];
    __shared__ short Bsl[64][72];
    __shared__ float Gs[64][65];
    const int t = threadIdx.x;
    const int wid = t >> 6, lane = t & 63;
    const int wm = wid & 1, wn = wid >> 1;
    const int quad = lane >> 4, l15 = lane & 15;
    const long j0 = (long)blockIdx.x * 64;
    const long d0 = (long)blockIdx.y * 64;
    f32x4 acc[2][2];
#pragma unroll
    for (int i = 0; i < 2; ++i)
#pragma unroll
        for (int j = 0; j < 2; ++j)
#pragma unroll
            for (int r = 0; r < 4; ++r) acc[i][j][r] = 0.f;

    for (int kb = 0; kb < 256; kb += 64) {
#pragma unroll
        for (int it = 0; it < 2; ++it) {
            const int cid = t + it * 256;
            const int row = cid >> 3, c8 = (cid & 7) * 8;
            const float rd = fastrcp(C1[(j0 + row) * 288 + 256]);
            const float* ap = C1 + (j0 + row) * 288 + kb + c8;
            f32x4 v0 = *reinterpret_cast<const f32x4*>(ap);
            f32x4 v1 = *reinterpret_cast<const f32x4*>(ap + 4);
            short8 hi, lo;
#pragma unroll
            for (int k = 0; k < 4; ++k) {
                float f0 = leakyf(v0[k] * rd);
                float f1 = leakyf(v1[k] * rd);
                short h0 = f2b(f0); hi[k] = h0; lo[k] = f2b(f0 - b2f(h0));
                short h1 = f2b(f1); hi[4 + k] = h1; lo[4 + k] = f2b(f1 - b2f(h1));
            }
            *reinterpret_cast<short8*>(&Ash[row][c8]) = hi;
            *reinterpret_cast<short8*>(&Asl[row][c8]) = lo;
            *reinterpret_cast<short8*>(&Bsh[row][c8]) =
                *reinterpret_cast<const short8*>(w2Th + (d0 + row) * 256 + kb + c8);
            *reinterpret_cast<short8*>(&Bsl[row][c8]) =
                *reinterpret_cast<const short8*>(w2Tl + (d0 + row) * 256 + kb + c8);
        }
        __syncthreads();
#pragma unroll
        for (int ks = 0; ks < 2; ++ks) {
            short8 ah[2], al[2], bh[2], bl[2];
#pragma unroll
            for (int i = 0; i < 2; ++i) {
                ah[i] = *reinterpret_cast<const short8*>(&Ash[wm * 32 + i * 16 + l15][ks * 32 + quad * 8]);
                al[i] = *reinterpret_cast<const short8*>(&Asl[wm * 32 + i * 16 + l15][ks * 32 + quad * 8]);
            }
#pragma unroll
            for (int j = 0; j < 2; ++j) {
                bh[j] = *reinterpret_cast<const short8*>(&Bsh[wn * 32 + j * 16 + l15][ks * 32 + quad * 8]);
                bl[j] = *reinterpret_cast<const short8*>(&Bsl[wn * 32 + j * 16 + l15][ks * 32 + quad * 8]);
            }
#pragma unroll
            for (int i = 0; i < 2; ++i)
#pragma unroll
                for (int j = 0; j < 2; ++j) {
                    acc[i][j] = __builtin_amdgcn_mfma_f32_16x16x32_bf16(ah[i], bh[j], acc[i][j], 0, 0, 0);
                    acc[i][j] = __builtin_amdgcn_mfma_f32_16x16x32_bf16(ah[i], bl[j], acc[i][j], 0, 0, 0);
                    acc[i][j] = __builtin_amdgcn_mfma_f32_16x16x32_bf16(al[i], bh[j], acc[i][j], 0, 0, 0);
                }
        }
        __syncthreads();
    }
#pragma unroll
    for (int i = 0; i < 2; ++i)
#pragma unroll
        for (int j = 0; j < 2; ++j)
#pragma unroll
            for (int r = 0; r < 4; ++r)
                Gs[wm * 32 + i * 16 + quad * 4 + r][wn * 32 + j * 16 + l15] = acc[i][j][r];
    __syncthreads();
    {
        const int jl = t >> 2, q = t & 3;
        float cp = 0.f;
#pragma unroll
        for (int i = 0; i < 16; ++i) {
            const int d = q * 16 + i;
            cp += leakyf(Gs[jl][d]) * a21[d0 + d];
        }
        cp += __shfl_xor(cp, 1); cp += __shfl_xor(cp, 2);
        if (q == 0) atomicAdd(&cat[j0 + jl], cp);
    }
    {
        const int dl = t >> 2, q = t & 3;
        short8 pk0, pk1;
#pragma unroll
        for (int i = 0; i < 8; ++i) pk0[i] = f2b(Gs[q * 16 + i][dl]);
#pragma unroll
        for (int i = 0; i < 8; ++i) pk1[i] = f2b(Gs[q * 16 + 8 + i][dl]);
        short* gp = GT + (d0 + dl) * 4096 + j0 + q * 16;
        *reinterpret_cast<short8*>(gp) = pk0;
        *reinterpret_cast<short8*>(gp + 8) = pk1;
    }
}

// ---------------------------------------------------------------- FUSED edge weights + final GEMM
// out[m0+r, :] = leaky( (B @ G) / rowsum ),  B computed on the fly per K-tile.
// BM=64 rows, BN=256 (full D), BK=64, grid (256), 256 threads.
__global__ __launch_bounds__(256) void fused_out(
        const unsigned int* __restrict__ Hbits, const float* __restrict__ cat,
        const float* __restrict__ dn, const short* __restrict__ GT,
        float* __restrict__ out) {
    __shared__ float catS[4096];            // 16 KB
    __shared__ unsigned int bitsS[64][132]; // 33.8 KB (132: rows 16B-aligned)
    __shared__ short As[64][72];            // 9.2 KB  (B-tile, bf16)
    __shared__ short Bs[256][72];           // 36.9 KB (GT tile)
    __shared__ float rsS[64][4];
    __shared__ float rinvS[64];
    const int t = threadIdx.x;
    const int wid = t >> 6, lane = t & 63;
    const int wm = wid & 1, wn = wid >> 1;
    const int quad = lane >> 4, l15 = lane & 15;
    const long m0 = (long)blockIdx.x * 64;
    const int r = t & 63, jc = t >> 6;       // Bvals role: row r, j-chunk jc
    const float drow = dn[m0 + r];

#pragma unroll
    for (int i = 0; i < 4; ++i) {
        f32x4 v = *reinterpret_cast<const f32x4*>(cat + t * 16 + i * 4);
        *reinterpret_cast<f32x4*>(&catS[t * 16 + i * 4]) = v;
    }
#pragma unroll
    for (int it = 0; it < 8; ++it) {
        const int cid = t + it * 256;
        const int row = cid >> 5, ch = (cid & 31) * 4;
        *reinterpret_cast<uint4v*>(&bitsS[row][ch]) =
            *reinterpret_cast<const uint4v*>(Hbits + (m0 + row) * 128 + ch);
    }

    f32x4 acc[2][8];
#pragma unroll
    for (int i = 0; i < 2; ++i)
#pragma unroll
        for (int j = 0; j < 8; ++j)
#pragma unroll
            for (int x = 0; x < 4; ++x) acc[i][j][x] = 0.f;
    float racc = 0.f;
    __syncthreads();   // bitsS/catS ready

    for (int kb = 0; kb < 4096; kb += 64) {
        // stage GT tile: 256 rows x 64 cols bf16
#pragma unroll
        for (int it = 0; it < 8; ++it) {
            const int cid = t + it * 256;
            const int row = cid >> 3, c8 = (cid & 7) * 8;
            *reinterpret_cast<short8*>(&Bs[row][c8]) =
                *reinterpret_cast<const short8*>(GT + row * 4096 + kb + c8);
        }
        // compute B-tile values from bits + satexp(c_j + d_n)
        {
            const unsigned int w = bitsS[r][(kb >> 5) + (jc >> 1)];
            const int bo = (jc & 1) * 16;
            short8 pk0, pk1;
#pragma unroll
            for (int c = 0; c < 4; ++c) {
                f32x4 cv = *reinterpret_cast<const f32x4*>(&catS[kb + jc * 16 + c * 4]);
#pragma unroll
                for (int k = 0; k < 4; ++k) {
                    const int kk = c * 4 + k;
                    const float s = ((w >> (bo + kk)) & 1u) ? satexpf(cv[k] + drow) : 0.f;
                    const short sb = f2b(s);
                    if (kk < 8) pk0[kk] = sb; else pk1[kk - 8] = sb;
                    racc += b2f(sb);
                }
            }
            *reinterpret_cast<short8*>(&As[r][jc * 16]) = pk0;
            *reinterpret_cast<short8*>(&As[r][jc * 16 + 8]) = pk1;
        }
        __syncthreads();
#pragma unroll
        for (int ks = 0; ks < 2; ++ks) {
            short8 af[2], bf[8];
#pragma unroll
            for (int i = 0; i < 2; ++i)
                af[i] = *reinterpret_cast<const short8*>(
                        &As[wm * 32 + i * 16 + l15][ks * 32 + quad * 8]);
#pragma unroll
            for (int j = 0; j < 8; ++j)
                bf[j] = *reinterpret_cast<const short8*>(
                        &Bs[wn * 128 + j * 16 + l15][ks * 32 + quad * 8]);
#pragma unroll
            for (int i = 0; i < 2; ++i)
#pragma unroll
                for (int j = 0; j < 8; ++j)
                    acc[i][j] = __builtin_amdgcn_mfma_f32_16x16x32_bf16(
                            af[i], bf[j], acc[i][j], 0, 0, 0);
        }
        __syncthreads();
    }
    // rowsum (from rounded bf16 values, matching what the GEMM consumed)
    rsS[r][jc] = racc;
    __syncthreads();
    if (t < 64)
        rinvS[t] = fastrcp(rsS[t][0] + rsS[t][1] + rsS[t][2] + rsS[t][3]);
    __syncthreads();
#pragma unroll
    for (int i = 0; i < 2; ++i) {
#pragma unroll
        for (int j = 0; j < 8; ++j) {
            const long gcol = wn * 128 + j * 16 + l15;
#pragma unroll
            for (int x = 0; x < 4; ++x) {
                const int rl = wm * 32 + i * 16 + quad * 4 + x;
                out[(m0 + rl) * 256 + gcol] = leakyf(acc[i][j][x] * rinvS[rl]);
            }
        }
    }
}

// ---------------------------------------------------------------- launch
extern "C" void kernel_launch(void* const* d_in, const int* in_sizes, int n_in,
                              void* d_out, int out_size, void* d_ws, size_t ws_size,
                              hipStream_t stream) {
    const float* x   = (const float*)d_in[0];
    const float* H   = (const float*)d_in[1];
    const float* w1  = (const float*)d_in[2];
    const float* w2  = (const float*)d_in[3];
    const float* a1  = (const float*)d_in[4];
    const float* a21 = (const float*)d_in[5];
    const float* a22 = (const float*)d_in[6];
    float* out = (float*)d_out;
    char* ws = (char*)d_ws;

    // region0 [0,64MB): xw1 fp32 (16.8MB) -> C1p fp32 [8][4096][288] (37.75MB)
    // HbT i8 [64MB,128MB).  (Bmat no longer exists -- fused away.)
    float* xw1   = (float*)(ws + 0);
    float* C1p   = (float*)(ws + 0);
    char*  HbT   = (char*)(ws + 67108864);
    char*  yQ    = (char*)(ws + 134217728);               // [576,16384] i8
    float* dn    = (float*)(ws + 143654912);              // [16384]
    float* g     = (float*)(ws + 143720448);              // [16384]
    unsigned int* ddmax = (unsigned int*)(ws + 143785984);// [288]
    short* w1Th  = (short*)(ws + 143790080);
    short* w1Tl  = (short*)(ws + 143921152);
    short* w2Th  = (short*)(ws + 144052224);
    short* w2Tl  = (short*)(ws + 144183296);
    float* C1    = (float*)(ws + 144314368);              // [4096,288]
    short* GT    = (short*)(ws + 149032960);              // [256,4096] bf16
    float* cat   = (float*)(ws + 151130112);              // [4096]
    unsigned int* Hbits = (unsigned int*)(ws + 151212032);// [16384,128]

    hipMemsetAsync(ddmax, 0, 288 * sizeof(unsigned int), stream);
    hipMemsetAsync(cat, 0, 4096 * sizeof(float), stream);

    transpose_split2<<<dim3(4, 4, 2), 256, 0, stream>>>(
            w1, w1Th, w1Tl, w2, w2Th, w2Tl);
    transposeH_pack<<<dim3(256, 64), 256, 0, stream>>>(H, HbT, Hbits);

    gemm_xw1<<<dim3(128, 4), 256, 0, stream>>>(x, w1Th, w1Tl, xw1);
    node_stats1<<<dim3(256), 256, 0, stream>>>(xw1, a1, a22, g, dn, ddmax);
    quantize_y<<<dim3(256), 256, 0, stream>>>(xw1, g, ddmax, yQ);

    gemm_c1_i8<<<dim3(32, 3, 8), 256, 0, stream>>>(HbT, yQ, C1p);
    reduce_C1<<<dim3(4608), 256, 0, stream>>>(C1p, ddmax, C1);

    gemm_G<<<dim3(64, 4), 256, 0, stream>>>(C1, w2Th, w2Tl, a21, GT, cat);

    fused_out<<<dim3(256), 256, 0, stream>>>(Hbits, cat, dn, GT, out);
}

// Round 7
// 675.568 us; speedup vs baseline: 1.0103x; 1.0103x over previous
//
#include <hip/hip_runtime.h>

// HyperGAT layer, N=16384, E=4096, D=256 on gfx950.
//   xw1 = x@w1 (split-bf16 MFMA, ~fp32 accurate)
//   g_n = satexp(leaky(xw1)@a1), d_n = leaky(xw1)@a22
//   y = g*xw1 quantized to i16 (per-dd global scale), split qh/ql i8 planes
//   C1 = H^T @ [qh|ql]  (i8 MFMA; A expanded from j-major bit-pack in LDS)
//   f2 = leaky(C1/den);  G = f2@w2 (split);  c_j = leaky(G)@a21
//   out = leaky((B@G)/rowsum), B[n,j] = Hbit*satexp(c_j+d_n) on the fly.

typedef __attribute__((ext_vector_type(8))) short short8;
typedef __attribute__((ext_vector_type(4))) float f32x4;
typedef __attribute__((ext_vector_type(4))) int int4v;
typedef __attribute__((ext_vector_type(4))) unsigned int uint4v;

__device__ __forceinline__ float leakyf(float v) { return v > 0.f ? v : 0.1f * v; }
__device__ __forceinline__ float fastrcp(float x) { return __builtin_amdgcn_rcpf(x); }

__device__ __forceinline__ float satexpf(float t) {
    float u = fminf(fmaxf(t * 0.25f, -30.f), 30.f);
    float p = __expf(u);
    float th = (p - 1.f) * fastrcp(p + 1.f);
    return __expf(8.f * th);
}

__device__ __forceinline__ short f2b(float v) {
    unsigned int x = __float_as_uint(v);
    x += 0x7fffu + ((x >> 16) & 1u);
    return (short)(x >> 16);
}
__device__ __forceinline__ float b2f(short s) {
    return __uint_as_float(((unsigned int)(unsigned short)s) << 16);
}
// 4 H-bits -> 4 i8 bytes (bit-deposit via magic multiply)
__device__ __forceinline__ unsigned int bits4_to_bytes(unsigned int s) {
    return ((s & 0xFu) * 0x00204081u) & 0x01010101u;
}

// ---------------------------------------------------------------- weight transposes (w1,w2) + hi/lo split
__global__ __launch_bounds__(256) void transpose_split2(
        const float* __restrict__ s0, short* __restrict__ dh0, short* __restrict__ dl0,
        const float* __restrict__ s1, short* __restrict__ dh1, short* __restrict__ dl1) {
    const float* src = blockIdx.z ? s1 : s0;
    short* dh = blockIdx.z ? dh1 : dh0;
    short* dl = blockIdx.z ? dl1 : dl0;
    __shared__ float Ts[64][65];
    const int t = threadIdx.x;
    const long r0 = (long)blockIdx.x * 64;
    const long c0 = (long)blockIdx.y * 64;
    {
        const int row = t >> 2, cc = (t & 3) * 16;
        const float* p = src + (r0 + row) * 256 + c0 + cc;
#pragma unroll
        for (int i = 0; i < 4; ++i) {
            f32x4 v = *reinterpret_cast<const f32x4*>(p + i * 4);
#pragma unroll
            for (int k = 0; k < 4; ++k) Ts[row][cc + i * 4 + k] = v[k];
        }
    }
    __syncthreads();
    {
        const int cl = t >> 2, ch = (t & 3) * 16;
        short8 h0, h1, l0, l1;
#pragma unroll
        for (int i = 0; i < 8; ++i) {
            float v = Ts[ch + i][cl];
            short h = f2b(v);
            h0[i] = h; l0[i] = f2b(v - b2f(h));
        }
#pragma unroll
        for (int i = 0; i < 8; ++i) {
            float v = Ts[ch + 8 + i][cl];
            short h = f2b(v);
            h1[i] = h; l1[i] = f2b(v - b2f(h));
        }
        short* qh = dh + (c0 + cl) * 256 + r0 + ch;
        short* ql = dl + (c0 + cl) * 256 + r0 + ch;
        *reinterpret_cast<short8*>(qh) = h0;
        *reinterpret_cast<short8*>(qh + 8) = h1;
        *reinterpret_cast<short8*>(ql) = l0;
        *reinterpret_cast<short8*>(ql + 8) = l1;
    }
}

// ---------------------------------------------------------------- H -> Hbits (n-major) + HbitsT (j-major)
__global__ __launch_bounds__(256) void transposeH_pack(
        const float* __restrict__ H, unsigned int* __restrict__ Hbits,
        unsigned int* __restrict__ HbitsT) {
    __shared__ float Ts[64][65];
    const int t = threadIdx.x;
    const long r0 = (long)blockIdx.x * 64;   // n
    const long c0 = (long)blockIdx.y * 64;   // j
    {
        const int row = t >> 2, cc = (t & 3) * 16;
        const float* p = H + (r0 + row) * 4096L + c0 + cc;
#pragma unroll
        for (int i = 0; i < 4; ++i) {
            f32x4 v = *reinterpret_cast<const f32x4*>(p + i * 4);
#pragma unroll
            for (int k = 0; k < 4; ++k) Ts[row][cc + i * 4 + k] = v[k];
        }
    }
    __syncthreads();
    if (t < 128) {           // Hbits: row n, bits over j
        const int nl = t >> 1, w = t & 1;
        unsigned int u = 0;
#pragma unroll
        for (int b = 0; b < 32; ++b)
            u |= (Ts[nl][w * 32 + b] != 0.f ? 1u : 0u) << b;
        Hbits[(r0 + nl) * 128 + (c0 >> 5) + w] = u;
    } else {                 // HbitsT: row j, bits over n
        const int t2 = t - 128;
        const int jl = t2 >> 1, w = t2 & 1;
        unsigned int u = 0;
#pragma unroll
        for (int b = 0; b < 32; ++b)
            u |= (Ts[w * 32 + b][jl] != 0.f ? 1u : 0u) << b;
        HbitsT[(c0 + jl) * 512 + (r0 >> 5) + w] = u;
    }
}

// ---------------------------------------------------------------- xw1 split GEMM (fp32-accurate)
__global__ __launch_bounds__(256) void gemm_xw1(
        const float* __restrict__ A, const short* __restrict__ Bh,
        const short* __restrict__ Bl, float* __restrict__ C) {
    __shared__ short Ash[128][72];
    __shared__ short Asl[128][72];
    __shared__ short Bsh[64][72];
    __shared__ short Bsl[64][72];
    const int t = threadIdx.x;
    const int wid = t >> 6, lane = t & 63;
    const int wm = wid & 1, wn = wid >> 1;
    const int quad = lane >> 4, l15 = lane & 15;
    const long m0 = (long)blockIdx.x * 128;
    const long n0 = (long)blockIdx.y * 64;
    f32x4 acc[4][2];
#pragma unroll
    for (int i = 0; i < 4; ++i)
#pragma unroll
        for (int j = 0; j < 2; ++j)
#pragma unroll
            for (int r = 0; r < 4; ++r) acc[i][j][r] = 0.f;

    for (int kb = 0; kb < 256; kb += 64) {
#pragma unroll
        for (int it = 0; it < 4; ++it) {
            const int cid = t + it * 256;
            const int row = cid >> 3, c8 = (cid & 7) * 8;
            const float* ap = A + (m0 + row) * 256 + kb + c8;
            f32x4 v0 = *reinterpret_cast<const f32x4*>(ap);
            f32x4 v1 = *reinterpret_cast<const f32x4*>(ap + 4);
            short8 hi, lo;
#pragma unroll
            for (int k = 0; k < 4; ++k) {
                short h0 = f2b(v0[k]); hi[k] = h0; lo[k] = f2b(v0[k] - b2f(h0));
                short h1 = f2b(v1[k]); hi[4 + k] = h1; lo[4 + k] = f2b(v1[k] - b2f(h1));
            }
            *reinterpret_cast<short8*>(&Ash[row][c8]) = hi;
            *reinterpret_cast<short8*>(&Asl[row][c8]) = lo;
        }
#pragma unroll
        for (int it = 0; it < 2; ++it) {
            const int cid = t + it * 256;
            const int row = cid >> 3, c8 = (cid & 7) * 8;
            *reinterpret_cast<short8*>(&Bsh[row][c8]) =
                *reinterpret_cast<const short8*>(Bh + (n0 + row) * 256 + kb + c8);
            *reinterpret_cast<short8*>(&Bsl[row][c8]) =
                *reinterpret_cast<const short8*>(Bl + (n0 + row) * 256 + kb + c8);
        }
        __syncthreads();
#pragma unroll
        for (int ks = 0; ks < 2; ++ks) {
            short8 ah[4], al[4], bh[2], bl[2];
#pragma unroll
            for (int i = 0; i < 4; ++i) {
                ah[i] = *reinterpret_cast<const short8*>(&Ash[wm * 64 + i * 16 + l15][ks * 32 + quad * 8]);
                al[i] = *reinterpret_cast<const short8*>(&Asl[wm * 64 + i * 16 + l15][ks * 32 + quad * 8]);
            }
#pragma unroll
            for (int j = 0; j < 2; ++j) {
                bh[j] = *reinterpret_cast<const short8*>(&Bsh[wn * 32 + j * 16 + l15][ks * 32 + quad * 8]);
                bl[j] = *reinterpret_cast<const short8*>(&Bsl[wn * 32 + j * 16 + l15][ks * 32 + quad * 8]);
            }
#pragma unroll
            for (int i = 0; i < 4; ++i)
#pragma unroll
                for (int j = 0; j < 2; ++j) {
                    acc[i][j] = __builtin_amdgcn_mfma_f32_16x16x32_bf16(ah[i], bh[j], acc[i][j], 0, 0, 0);
                    acc[i][j] = __builtin_amdgcn_mfma_f32_16x16x32_bf16(ah[i], bl[j], acc[i][j], 0, 0, 0);
                    acc[i][j] = __builtin_amdgcn_mfma_f32_16x16x32_bf16(al[i], bh[j], acc[i][j], 0, 0, 0);
                }
        }
        __syncthreads();
    }
#pragma unroll
    for (int i = 0; i < 4; ++i) {
        const long grow = m0 + wm * 64 + i * 16 + quad * 4;
#pragma unroll
        for (int j = 0; j < 2; ++j) {
            const long gcol = n0 + wn * 32 + j * 16 + l15;
#pragma unroll
            for (int r = 0; r < 4; ++r)
                C[(grow + r) * 256 + gcol] = acc[i][j][r];
        }
    }
}

// ---------------------------------------------------------------- node stats: g, dn, per-dd |y| max
__global__ __launch_bounds__(256) void node_stats1(
        const float* __restrict__ xw1, const float* __restrict__ a1,
        const float* __restrict__ a22, float* __restrict__ g_out,
        float* __restrict__ dn, unsigned int* __restrict__ ddmax) {
    __shared__ float Mx[4][260];
    const int t = threadIdx.x;
    const int n0 = blockIdx.x * 64;
    const int r = t >> 2, q = t & 3;
    const long n = n0 + r;
    const float* xp = xw1 + n * 256 + q * 64;
    float vals[64];
    float facc = 0.f, dacc = 0.f;
#pragma unroll
    for (int i = 0; i < 16; ++i) {
        f32x4 v  = *reinterpret_cast<const f32x4*>(xp + i * 4);
        f32x4 b1 = *reinterpret_cast<const f32x4*>(a1 + q * 64 + i * 4);
        f32x4 b2 = *reinterpret_cast<const f32x4*>(a22 + q * 64 + i * 4);
#pragma unroll
        for (int k = 0; k < 4; ++k) {
            float lv = leakyf(v[k]);
            facc += lv * b1[k];
            dacc += lv * b2[k];
            vals[i * 4 + k] = v[k];
        }
    }
    facc += __shfl_xor(facc, 1); facc += __shfl_xor(facc, 2);
    dacc += __shfl_xor(dacc, 1); dacc += __shfl_xor(dacc, 2);
    const float g = satexpf(facc);
    if (q == 0) { dn[n] = dacc; g_out[n] = g; }
    float lm[64];
#pragma unroll
    for (int i = 0; i < 64; ++i) lm[i] = fabsf(vals[i] * g);
#pragma unroll
    for (int m = 4; m < 64; m <<= 1)
#pragma unroll
        for (int i = 0; i < 64; ++i) lm[i] = fmaxf(lm[i], __shfl_xor(lm[i], m));
    float gm = g;
#pragma unroll
    for (int m = 1; m < 64; m <<= 1) gm = fmaxf(gm, __shfl_xor(gm, m));
    const int wv = t >> 6, lane = t & 63;
    if (lane < 4) {
#pragma unroll
        for (int i = 0; i < 64; ++i) Mx[wv][lane * 64 + i] = lm[i];
    }
    if (lane == 0) Mx[wv][256] = gm;
    __syncthreads();
    if (t < 256) {
        float m = fmaxf(fmaxf(Mx[0][t], Mx[1][t]), fmaxf(Mx[2][t], Mx[3][t]));
        atomicMax(&ddmax[t], __float_as_uint(m));
    }
    if (t == 0) {  // index 256 (g); block has only 256 threads
        float m = fmaxf(fmaxf(Mx[0][256], Mx[1][256]), fmaxf(Mx[2][256], Mx[3][256]));
        atomicMax(&ddmax[256], __float_as_uint(m));
    }
}

// ---------------------------------------------------------------- quantize y -> yQ i8 [576,16384]
__global__ __launch_bounds__(256) void quantize_y(
        const float* __restrict__ xw1, const float* __restrict__ g_in,
        const unsigned int* __restrict__ ddmax, char* __restrict__ yQ) {
    __shared__ unsigned int Qh[257][16];
    __shared__ unsigned int Ql[257][16];
    const int t = threadIdx.x;
    const int n0 = blockIdx.x * 64;
    const int dd0 = (t >> 4) * 16;
    const int w = t & 15;
    const int r4 = w * 4;
    float s[16];
#pragma unroll
    for (int i = 0; i < 16; ++i)
        s[i] = 32512.f / __uint_as_float(ddmax[dd0 + i]);
    const float sg = 32512.f / __uint_as_float(ddmax[256]);
    unsigned int bh[16], bl[16];
#pragma unroll
    for (int i = 0; i < 16; ++i) { bh[i] = 0u; bl[i] = 0u; }
    unsigned int gh = 0u, gl = 0u;
#pragma unroll
    for (int rr = 0; rr < 4; ++rr) {
        const long n = n0 + r4 + rr;
        const float gg = g_in[n];
        const float* xp = xw1 + n * 256 + dd0;
#pragma unroll
        for (int c = 0; c < 4; ++c) {
            f32x4 v = *reinterpret_cast<const f32x4*>(xp + c * 4);
#pragma unroll
            for (int k = 0; k < 4; ++k) {
                const int i = c * 4 + k;
                int qv = __float2int_rn(v[k] * gg * s[i]);
                qv = max(-32639, min(32639, qv));
                const int qh = (qv + 128) >> 8;
                const int ql = qv - (qh << 8);
                bh[i] |= ((unsigned int)(qh & 255)) << (8 * rr);
                bl[i] |= ((unsigned int)(ql & 255)) << (8 * rr);
            }
        }
        if (t < 16) {
            int qv = __float2int_rn(gg * sg);
            qv = max(-32639, min(32639, qv));
            const int qh = (qv + 128) >> 8;
            const int ql = qv - (qh << 8);
            gh |= ((unsigned int)(qh & 255)) << (8 * rr);
            gl |= ((unsigned int)(ql & 255)) << (8 * rr);
        }
    }
#pragma unroll
    for (int i = 0; i < 16; ++i) { Qh[dd0 + i][w] = bh[i]; Ql[dd0 + i][w] = bl[i]; }
    if (t < 16) { Qh[256][t] = gh; Ql[256][t] = gl; }
    __syncthreads();
#pragma unroll
    for (int it = 0; it < 2; ++it) {
        const int dd = it * 256 + t;
        if (dd < 288) {
#pragma unroll
            for (int s2 = 0; s2 < 4; ++s2) {
                uint4v vh, vl;
                if (dd < 257) {
                    vh = *reinterpret_cast<const uint4v*>(&Qh[dd][s2 * 4]);
                    vl = *reinterpret_cast<const uint4v*>(&Ql[dd][s2 * 4]);
                } else {
#pragma unroll
                    for (int k = 0; k < 4; ++k) { vh[k] = 0u; vl[k] = 0u; }
                }
                *reinterpret_cast<uint4v*>(yQ + (long)dd * 16384 + n0 + s2 * 16) = vh;
                *reinterpret_cast<uint4v*>(yQ + (long)(288 + dd) * 16384 + n0 + s2 * 16) = vl;
            }
        }
    }
}

// ---------------------------------------------------------------- C1 GEMM, i8 MFMA, A expanded from bits in LDS
// BM=256 (j), BN=48 (dd), BK=128, z=4 (Ktile 4096), grid (16, 6, 4).
// Cp fp32 [4][4096][288] = 256*hi + lo partials.
__global__ __launch_bounds__(256) void gemm_c1_bits(
        const unsigned int* __restrict__ HbitsT, const char* __restrict__ Bb,
        float* __restrict__ Cp) {
    __shared__ char As[256][144];   // 36.9 KB
    __shared__ char Bsh[48][144];   // 6.9 KB
    __shared__ char Bsl[48][144];   // 6.9 KB
    const int t = threadIdx.x;
    const int wid = t >> 6, lane = t & 63;
    const int quad = lane >> 4, l15 = lane & 15;
    const long m0 = (long)blockIdx.x * 256;
    const long n0 = (long)blockIdx.y * 48;
    const long k0 = (long)blockIdx.z * 4096;
    float* Cz = Cp + (long)blockIdx.z * (4096L * 288);
    int4v acch[4][3], accl[4][3];
#pragma unroll
    for (int i = 0; i < 4; ++i)
#pragma unroll
        for (int j = 0; j < 3; ++j)
#pragma unroll
            for (int r = 0; r < 4; ++r) { acch[i][j][r] = 0; accl[i][j][r] = 0; }

    for (int kb = 0; kb < 4096; kb += 128) {
        // A: expand 128 H-bits of row (m0+t) into 128 i8
        {
            uint4v bv = *reinterpret_cast<const uint4v*>(
                    HbitsT + (m0 + t) * 512 + ((k0 + kb) >> 5));
#pragma unroll
            for (int w4 = 0; w4 < 4; ++w4) {
                const unsigned int u = bv[w4];
                uint4v e0, e1;
#pragma unroll
                for (int k = 0; k < 4; ++k) e0[k] = bits4_to_bytes(u >> (4 * k));
#pragma unroll
                for (int k = 0; k < 4; ++k) e1[k] = bits4_to_bytes(u >> (16 + 4 * k));
                *reinterpret_cast<uint4v*>(&As[t][w4 * 32]) = e0;
                *reinterpret_cast<uint4v*>(&As[t][w4 * 32 + 16]) = e1;
            }
        }
        // B: 48 rows x 128 B x 2 planes = 768 x 16B chunks.
        // BUGFIX (round 6): was `cid & 383` -- 383 is NOT a pow2 mask, left
        // Bsl rows 16..31 unwritten (incl. the den column dd=256) -> absmax 5810.
#pragma unroll
        for (int it = 0; it < 3; ++it) {
            const int cid = t + it * 256;
            const int idx = (cid < 384) ? cid : cid - 384;
            const int row = idx >> 3, seg = (idx & 7) * 16;
            char* dst = (cid >= 384) ? &Bsl[row][seg] : &Bsh[row][seg];
            const long srow = (cid >= 384) ? (288 + n0 + row) : (n0 + row);
            *reinterpret_cast<uint4v*>(dst) =
                *reinterpret_cast<const uint4v*>(Bb + srow * 16384 + k0 + kb + seg);
        }
        __syncthreads();
#pragma unroll
        for (int ks = 0; ks < 2; ++ks) {
            int4v af[4], bh[3], bl[3];
#pragma unroll
            for (int i = 0; i < 4; ++i)
                af[i] = *reinterpret_cast<const int4v*>(
                        &As[wid * 64 + i * 16 + l15][ks * 64 + quad * 16]);
#pragma unroll
            for (int j = 0; j < 3; ++j) {
                bh[j] = *reinterpret_cast<const int4v*>(&Bsh[j * 16 + l15][ks * 64 + quad * 16]);
                bl[j] = *reinterpret_cast<const int4v*>(&Bsl[j * 16 + l15][ks * 64 + quad * 16]);
            }
#pragma unroll
            for (int i = 0; i < 4; ++i)
#pragma unroll
                for (int j = 0; j < 3; ++j) {
                    acch[i][j] = __builtin_amdgcn_mfma_i32_16x16x64_i8(af[i], bh[j], acch[i][j], 0, 0, 0);
                    accl[i][j] = __builtin_amdgcn_mfma_i32_16x16x64_i8(af[i], bl[j], accl[i][j], 0, 0, 0);
                }
        }
        __syncthreads();
    }
#pragma unroll
    for (int i = 0; i < 4; ++i) {
        const long grow = m0 + wid * 64 + i * 16 + quad * 4;
#pragma unroll
        for (int j = 0; j < 3; ++j) {
            const long gcol = n0 + j * 16 + l15;
#pragma unroll
            for (int r = 0; r < 4; ++r)
                Cz[(grow + r) * 288 + gcol] =
                    256.f * (float)acch[i][j][r] + (float)accl[i][j][r];
        }
    }
}

// ---------------------------------------------------------------- reduce split-K partials + reconstruct scale
__global__ __launch_bounds__(256) void reduce_C1(
        const float* __restrict__ C1p, const unsigned int* __restrict__ ddmax,
        float* __restrict__ C1) {
    const int i = blockIdx.x * 256 + threadIdx.x;   // < 4096*288
    const int dd = i % 288;
    float s = 0.f;
#pragma unroll
    for (int z = 0; z < 4; ++z) s += C1p[(long)z * 4096 * 288 + i];
    C1[i] = s * (__uint_as_float(ddmax[dd]) * (1.f / 32512.f));
}

// ---------------------------------------------------------------- G = f2@w2 split (+ GT bf16, c_j)
__global__ __launch_bounds__(256) void gemm_G(
        const float* __restrict__ C1, const short* __restrict__ w2Th,
        const short* __restrict__ w2Tl, const float* __restrict__ a21,
        short* __restrict__ GT, float* __restrict__ cat) {
    __shared__ short Ash[64][72];
    __shared__ short Asl[64][72];
    __shared__ short Bsh[64][72];
    __shared__ short Bsl[64][72];
    __shared__ float Gs[64][65];
    const int t = threadIdx.x;
    const int wid = t >> 6, lane = t & 63;
    const int wm = wid & 1, wn = wid >> 1;
    const int quad = lane >> 4, l15 = lane & 15;
    const long j0 = (long)blockIdx.x * 64;
    const long d0 = (long)blockIdx.y * 64;
    f32x4 acc[2][2];
#pragma unroll
    for (int i = 0; i < 2; ++i)
#pragma unroll
        for (int j = 0; j < 2; ++j)
#pragma unroll
            for (int r = 0; r < 4; ++r) acc[i][j][r] = 0.f;

    for (int kb = 0; kb < 256; kb += 64) {
#pragma unroll
        for (int it = 0; it < 2; ++it) {
            const int cid = t + it * 256;
            const int row = cid >> 3, c8 = (cid & 7) * 8;
            const float rd = fastrcp(C1[(j0 + row) * 288 + 256]);
            const float* ap = C1 + (j0 + row) * 288 + kb + c8;
            f32x4 v0 = *reinterpret_cast<const f32x4*>(ap);
            f32x4 v1 = *reinterpret_cast<const f32x4*>(ap + 4);
            short8 hi, lo;
#pragma unroll
            for (int k = 0; k < 4; ++k) {
                float f0 = leakyf(v0[k] * rd);
                float f1 = leakyf(v1[k] * rd);
                short h0 = f2b(f0); hi[k] = h0; lo[k] = f2b(f0 - b2f(h0));
                short h1 = f2b(f1); hi[4 + k] = h1; lo[4 + k] = f2b(f1 - b2f(h1));
            }
            *reinterpret_cast<short8*>(&Ash[row][c8]) = hi;
            *reinterpret_cast<short8*>(&Asl[row][c8]) = lo;
            *reinterpret_cast<short8*>(&Bsh[row][c8]) =
                *reinterpret_cast<const short8*>(w2Th + (d0 + row) * 256 + kb + c8);
            *reinterpret_cast<short8*>(&Bsl[row][c8]) =
                *reinterpret_cast<const short8*>(w2Tl + (d0 + row) * 256 + kb + c8);
        }
        __syncthreads();
#pragma unroll
        for (int ks = 0; ks < 2; ++ks) {
            short8 ah[2], al[2], bh[2], bl[2];
#pragma unroll
            for (int i = 0; i < 2; ++i) {
                ah[i] = *reinterpret_cast<const short8*>(&Ash[wm * 32 + i * 16 + l15][ks * 32 + quad * 8]);
                al[i] = *reinterpret_cast<const short8*>(&Asl[wm * 32 + i * 16 + l15][ks * 32 + quad * 8]);
            }
#pragma unroll
            for (int j = 0; j < 2; ++j) {
                bh[j] = *reinterpret_cast<const short8*>(&Bsh[wn * 32 + j * 16 + l15][ks * 32 + quad * 8]);
                bl[j] = *reinterpret_cast<const short8*>(&Bsl[wn * 32 + j * 16 + l15][ks * 32 + quad * 8]);
            }
#pragma unroll
            for (int i = 0; i < 2; ++i)
#pragma unroll
                for (int j = 0; j < 2; ++j) {
                    acc[i][j] = __builtin_amdgcn_mfma_f32_16x16x32_bf16(ah[i], bh[j], acc[i][j], 0, 0, 0);
                    acc[i][j] = __builtin_amdgcn_mfma_f32_16x16x32_bf16(ah[i], bl[j], acc[i][j], 0, 0, 0);
                    acc[i][j] = __builtin_amdgcn_mfma_f32_16x16x32_bf16(al[i], bh[j], acc[i][j], 0, 0, 0);
                }
        }
        __syncthreads();
    }
#pragma unroll
    for (int i = 0; i < 2; ++i)
#pragma unroll
        for (int j = 0; j < 2; ++j)
#pragma unroll
            for (int r = 0; r < 4; ++r)
                Gs[wm * 32 + i * 16 + quad * 4 + r][wn * 32 + j * 16 + l15] = acc[i][j][r];
    __syncthreads();
    {
        const int jl = t >> 2, q = t & 3;
        float cp = 0.f;
#pragma unroll
        for (int i = 0; i < 16; ++i) {
            const int d = q * 16 + i;
            cp += leakyf(Gs[jl][d]) * a21[d0 + d];
        }
        cp += __shfl_xor(cp, 1); cp += __shfl_xor(cp, 2);
        if (q == 0) atomicAdd(&cat[j0 + jl], cp);
    }
    {
        const int dl = t >> 2, q = t & 3;
        short8 pk0, pk1;
#pragma unroll
        for (int i = 0; i < 8; ++i) pk0[i] = f2b(Gs[q * 16 + i][dl]);
#pragma unroll
        for (int i = 0; i < 8; ++i) pk1[i] = f2b(Gs[q * 16 + 8 + i][dl]);
        short* gp = GT + (d0 + dl) * 4096 + j0 + q * 16;
        *reinterpret_cast<short8*>(gp) = pk0;
        *reinterpret_cast<short8*>(gp + 8) = pk1;
    }
}

// ---------------------------------------------------------------- FUSED edge weights + final GEMM
// 512 threads (8 waves), BM=64, BN=256, BK=64, grid (256).
__global__ __launch_bounds__(512) void fused_out(
        const unsigned int* __restrict__ Hbits, const float* __restrict__ cat,
        const float* __restrict__ dn, const short* __restrict__ GT,
        float* __restrict__ out) {
    __shared__ short As[64][72];    // 9.2 KB
    __shared__ short Bs[256][72];   // 36.9 KB
    __shared__ float rsS[64][8];
    __shared__ float rinvS[64];
    const int t = threadIdx.x;
    const int wid = t >> 6, lane = t & 63;
    const int wm = wid >> 2, wn = wid & 3;
    const int quad = lane >> 4, l15 = lane & 15;
    const long m0 = (long)blockIdx.x * 64;
    const int r = lane, jc8 = wid;          // B-value role: row r, 8-col chunk jc8
    const float drow = dn[m0 + r];
    const int bc = jc8 >> 2;                // word select within prefetch
    const int bo = (jc8 & 3) * 8;

    f32x4 acc[2][4];
#pragma unroll
    for (int i = 0; i < 2; ++i)
#pragma unroll
        for (int j = 0; j < 4; ++j)
#pragma unroll
            for (int x = 0; x < 4; ++x) acc[i][j][x] = 0.f;
    float racc = 0.f;

    for (int kb2 = 0; kb2 < 4096; kb2 += 128) {
        const uint4v bw = *reinterpret_cast<const uint4v*>(
                Hbits + (m0 + r) * 128 + (kb2 >> 5));
#pragma unroll
        for (int half = 0; half < 2; ++half) {
            const int kb = kb2 + half * 64;
            // stage GT tile 256x64
#pragma unroll
            for (int it = 0; it < 4; ++it) {
                const int cid = t + it * 512;
                const int row = cid >> 3, c8 = (cid & 7) * 8;
                *reinterpret_cast<short8*>(&Bs[row][c8]) =
                    *reinterpret_cast<const short8*>(GT + row * 4096 + kb + c8);
            }
            // compute 8 B-values for (row r, cols kb+jc8*8..+7)
            {
                const unsigned int w = bw[half * 2 + bc];
                f32x4 cv0 = *reinterpret_cast<const f32x4*>(cat + kb + jc8 * 8);
                f32x4 cv1 = *reinterpret_cast<const f32x4*>(cat + kb + jc8 * 8 + 4);
                short8 pk;
#pragma unroll
                for (int k = 0; k < 8; ++k) {
                    const float cvk = (k < 4) ? cv0[k & 3] : cv1[k & 3];
                    const float s = ((w >> (bo + k)) & 1u) ? satexpf(cvk + drow) : 0.f;
                    const short sb = f2b(s);
                    pk[k] = sb;
                    racc += b2f(sb);
                }
                *reinterpret_cast<short8*>(&As[r][jc8 * 8]) = pk;
            }
            __syncthreads();
#pragma unroll
            for (int ks = 0; ks < 2; ++ks) {
                short8 af[2], bf[4];
#pragma unroll
                for (int i = 0; i < 2; ++i)
                    af[i] = *reinterpret_cast<const short8*>(
                            &As[wm * 32 + i * 16 + l15][ks * 32 + quad * 8]);
#pragma unroll
                for (int j = 0; j < 4; ++j)
                    bf[j] = *reinterpret_cast<const short8*>(
                            &Bs[wn * 64 + j * 16 + l15][ks * 32 + quad * 8]);
#pragma unroll
                for (int i = 0; i < 2; ++i)
#pragma unroll
                    for (int j = 0; j < 4; ++j)
                        acc[i][j] = __builtin_amdgcn_mfma_f32_16x16x32_bf16(
                                af[i], bf[j], acc[i][j], 0, 0, 0);
            }
            __syncthreads();
        }
    }
    rsS[r][jc8] = racc;
    __syncthreads();
    if (t < 64) {
        float s = 0.f;
#pragma unroll
        for (int i = 0; i < 8; ++i) s += rsS[t][i];
        rinvS[t] = fastrcp(s);
    }
    __syncthreads();
#pragma unroll
    for (int i = 0; i < 2; ++i) {
#pragma unroll
        for (int j = 0; j < 4; ++j) {
            const long gcol = wn * 64 + j * 16 + l15;
#pragma unroll
            for (int x = 0; x < 4; ++x) {
                const int rl = wm * 32 + i * 16 + quad * 4 + x;
                out[(m0 + rl) * 256 + gcol] = leakyf(acc[i][j][x] * rinvS[rl]);
            }
        }
    }
}

// ---------------------------------------------------------------- launch
extern "C" void kernel_launch(void* const* d_in, const int* in_sizes, int n_in,
                              void* d_out, int out_size, void* d_ws, size_t ws_size,
                              hipStream_t stream) {
    const float* x   = (const float*)d_in[0];
    const float* H   = (const float*)d_in[1];
    const float* w1  = (const float*)d_in[2];
    const float* w2  = (const float*)d_in[3];
    const float* a1  = (const float*)d_in[4];
    const float* a21 = (const float*)d_in[5];
    const float* a22 = (const float*)d_in[6];
    float* out = (float*)d_out;
    char* ws = (char*)d_ws;

    // region0: xw1 fp32 (16.8MB) then C1p fp32 [4][4096][288] (18.9MB) -- sequential reuse
    float* xw1   = (float*)(ws + 0);
    float* C1p   = (float*)(ws + 0);
    char*  yQ    = (char*)(ws + 67108864);                // [576,16384] i8 (9.44MB)
    float* dn    = (float*)(ws + 76546048);               // [16384]
    float* g     = (float*)(ws + 76611584);               // [16384]
    unsigned int* ddmax = (unsigned int*)(ws + 76677120); // [288]
    short* w1Th  = (short*)(ws + 76681216);
    short* w1Tl  = (short*)(ws + 76812288);
    short* w2Th  = (short*)(ws + 76943360);
    short* w2Tl  = (short*)(ws + 77074432);
    float* C1    = (float*)(ws + 77205504);               // [4096,288]
    short* GT    = (short*)(ws + 81924096);               // [256,4096] bf16
    float* cat   = (float*)(ws + 84021248);               // [4096]
    unsigned int* Hbits  = (unsigned int*)(ws + 84037632);// [16384,128] (8MB)
    unsigned int* HbitsT = (unsigned int*)(ws + 92426240);// [4096,512]  (8MB)

    hipMemsetAsync(ddmax, 0, 288 * sizeof(unsigned int), stream);
    hipMemsetAsync(cat, 0, 4096 * sizeof(float), stream);

    transpose_split2<<<dim3(4, 4, 2), 256, 0, stream>>>(
            w1, w1Th, w1Tl, w2, w2Th, w2Tl);
    transposeH_pack<<<dim3(256, 64), 256, 0, stream>>>(H, Hbits, HbitsT);

    gemm_xw1<<<dim3(128, 4), 256, 0, stream>>>(x, w1Th, w1Tl, xw1);
    node_stats1<<<dim3(256), 256, 0, stream>>>(xw1, a1, a22, g, dn, ddmax);
    quantize_y<<<dim3(256), 256, 0, stream>>>(xw1, g, ddmax, yQ);

    gemm_c1_bits<<<dim3(16, 6, 4), 256, 0, stream>>>(HbitsT, yQ, C1p);
    reduce_C1<<<dim3(4608), 256, 0, stream>>>(C1p, ddmax, C1);

    gemm_G<<<dim3(64, 4), 256, 0, stream>>>(C1, w2Th, w2Tl, a21, GT, cat);

    fused_out<<<dim3(256), 512, 0, stream>>>(Hbits, cat, dn, GT, out);
}

// Round 8
// 642.652 us; speedup vs baseline: 1.0620x; 1.0512x over previous
//
#include <hip/hip_runtime.h>

// HyperGAT layer, N=16384, E=4096, D=256 on gfx950.
//   xw1 = x@w1 (split-bf16 MFMA, ~fp32 accurate)
//   g_n = satexp(leaky(xw1)@a1), d_n = leaky(xw1)@a22
//   y = g*xw1 quantized to i16 (per-dd global scale), split qh/ql i8 planes
//   C1 = H^T @ [qh|ql]  (i8 MFMA; A expanded from j-major bit-pack in LDS)
//   f2 = leaky(C1/den);  G = f2@w2 (split);  c_j = leaky(G)@a21
//   out = leaky((B@G)/rowsum), B[n,j] = Hbit*satexp(c_j+d_n) on the fly.

typedef __attribute__((ext_vector_type(8))) short short8;
typedef __attribute__((ext_vector_type(4))) short short4v;
typedef __attribute__((ext_vector_type(4))) float f32x4;
typedef __attribute__((ext_vector_type(4))) int int4v;
typedef __attribute__((ext_vector_type(4))) unsigned int uint4v;

__device__ __forceinline__ float leakyf(float v) { return v > 0.f ? v : 0.1f * v; }
__device__ __forceinline__ float fastrcp(float x) { return __builtin_amdgcn_rcpf(x); }

__device__ __forceinline__ float satexpf(float t) {
    float u = fminf(fmaxf(t * 0.25f, -30.f), 30.f);
    float p = __expf(u);
    float th = (p - 1.f) * fastrcp(p + 1.f);
    return __expf(8.f * th);
}

__device__ __forceinline__ short f2b(float v) {
    unsigned int x = __float_as_uint(v);
    x += 0x7fffu + ((x >> 16) & 1u);
    return (short)(x >> 16);
}
__device__ __forceinline__ float b2f(short s) {
    return __uint_as_float(((unsigned int)(unsigned short)s) << 16);
}
// 4 H-bits -> 4 i8 bytes (bit-deposit via magic multiply)
__device__ __forceinline__ unsigned int bits4_to_bytes(unsigned int s) {
    return ((s & 0xFu) * 0x00204081u) & 0x01010101u;
}

// ---------------------------------------------------------------- weight transposes (w1,w2) + hi/lo split
__global__ __launch_bounds__(256) void transpose_split2(
        const float* __restrict__ s0, short* __restrict__ dh0, short* __restrict__ dl0,
        const float* __restrict__ s1, short* __restrict__ dh1, short* __restrict__ dl1) {
    const float* src = blockIdx.z ? s1 : s0;
    short* dh = blockIdx.z ? dh1 : dh0;
    short* dl = blockIdx.z ? dl1 : dl0;
    __shared__ float Ts[64][65];
    const int t = threadIdx.x;
    const long r0 = (long)blockIdx.x * 64;
    const long c0 = (long)blockIdx.y * 64;
    {
        const int row = t >> 2, cc = (t & 3) * 16;
        const float* p = src + (r0 + row) * 256 + c0 + cc;
#pragma unroll
        for (int i = 0; i < 4; ++i) {
            f32x4 v = *reinterpret_cast<const f32x4*>(p + i * 4);
#pragma unroll
            for (int k = 0; k < 4; ++k) Ts[row][cc + i * 4 + k] = v[k];
        }
    }
    __syncthreads();
    {
        const int cl = t >> 2, ch = (t & 3) * 16;
        short8 h0, h1, l0, l1;
#pragma unroll
        for (int i = 0; i < 8; ++i) {
            float v = Ts[ch + i][cl];
            short h = f2b(v);
            h0[i] = h; l0[i] = f2b(v - b2f(h));
        }
#pragma unroll
        for (int i = 0; i < 8; ++i) {
            float v = Ts[ch + 8 + i][cl];
            short h = f2b(v);
            h1[i] = h; l1[i] = f2b(v - b2f(h));
        }
        short* qh = dh + (c0 + cl) * 256 + r0 + ch;
        short* ql = dl + (c0 + cl) * 256 + r0 + ch;
        *reinterpret_cast<short8*>(qh) = h0;
        *reinterpret_cast<short8*>(qh + 8) = h1;
        *reinterpret_cast<short8*>(ql) = l0;
        *reinterpret_cast<short8*>(ql + 8) = l1;
    }
}

// ---------------------------------------------------------------- H -> Hbits (n-major) + HbitsT (j-major)
__global__ __launch_bounds__(256) void transposeH_pack(
        const float* __restrict__ H, unsigned int* __restrict__ Hbits,
        unsigned int* __restrict__ HbitsT) {
    __shared__ float Ts[64][65];
    const int t = threadIdx.x;
    const long r0 = (long)blockIdx.x * 64;   // n
    const long c0 = (long)blockIdx.y * 64;   // j
    {
        const int row = t >> 2, cc = (t & 3) * 16;
        const float* p = H + (r0 + row) * 4096L + c0 + cc;
#pragma unroll
        for (int i = 0; i < 4; ++i) {
            f32x4 v = *reinterpret_cast<const f32x4*>(p + i * 4);
#pragma unroll
            for (int k = 0; k < 4; ++k) Ts[row][cc + i * 4 + k] = v[k];
        }
    }
    __syncthreads();
    if (t < 128) {           // Hbits: row n, bits over j
        const int nl = t >> 1, w = t & 1;
        unsigned int u = 0;
#pragma unroll
        for (int b = 0; b < 32; ++b)
            u |= (Ts[nl][w * 32 + b] != 0.f ? 1u : 0u) << b;
        Hbits[(r0 + nl) * 128 + (c0 >> 5) + w] = u;
    } else {                 // HbitsT: row j, bits over n
        const int t2 = t - 128;
        const int jl = t2 >> 1, w = t2 & 1;
        unsigned int u = 0;
#pragma unroll
        for (int b = 0; b < 32; ++b)
            u |= (Ts[w * 32 + b][jl] != 0.f ? 1u : 0u) << b;
        HbitsT[(c0 + jl) * 512 + (r0 >> 5) + w] = u;
    }
}

// ---------------------------------------------------------------- xw1 split GEMM (fp32-accurate)
__global__ __launch_bounds__(256) void gemm_xw1(
        const float* __restrict__ A, const short* __restrict__ Bh,
        const short* __restrict__ Bl, float* __restrict__ C) {
    __shared__ short Ash[128][72];
    __shared__ short Asl[128][72];
    __shared__ short Bsh[64][72];
    __shared__ short Bsl[64][72];
    const int t = threadIdx.x;
    const int wid = t >> 6, lane = t & 63;
    const int wm = wid & 1, wn = wid >> 1;
    const int quad = lane >> 4, l15 = lane & 15;
    const long m0 = (long)blockIdx.x * 128;
    const long n0 = (long)blockIdx.y * 64;
    f32x4 acc[4][2];
#pragma unroll
    for (int i = 0; i < 4; ++i)
#pragma unroll
        for (int j = 0; j < 2; ++j)
#pragma unroll
            for (int r = 0; r < 4; ++r) acc[i][j][r] = 0.f;

    for (int kb = 0; kb < 256; kb += 64) {
#pragma unroll
        for (int it = 0; it < 4; ++it) {
            const int cid = t + it * 256;
            const int row = cid >> 3, c8 = (cid & 7) * 8;
            const float* ap = A + (m0 + row) * 256 + kb + c8;
            f32x4 v0 = *reinterpret_cast<const f32x4*>(ap);
            f32x4 v1 = *reinterpret_cast<const f32x4*>(ap + 4);
            short8 hi, lo;
#pragma unroll
            for (int k = 0; k < 4; ++k) {
                short h0 = f2b(v0[k]); hi[k] = h0; lo[k] = f2b(v0[k] - b2f(h0));
                short h1 = f2b(v1[k]); hi[4 + k] = h1; lo[4 + k] = f2b(v1[k] - b2f(h1));
            }
            *reinterpret_cast<short8*>(&Ash[row][c8]) = hi;
            *reinterpret_cast<short8*>(&Asl[row][c8]) = lo;
        }
#pragma unroll
        for (int it = 0; it < 2; ++it) {
            const int cid = t + it * 256;
            const int row = cid >> 3, c8 = (cid & 7) * 8;
            *reinterpret_cast<short8*>(&Bsh[row][c8]) =
                *reinterpret_cast<const short8*>(Bh + (n0 + row) * 256 + kb + c8);
            *reinterpret_cast<short8*>(&Bsl[row][c8]) =
                *reinterpret_cast<const short8*>(Bl + (n0 + row) * 256 + kb + c8);
        }
        __syncthreads();
#pragma unroll
        for (int ks = 0; ks < 2; ++ks) {
            short8 ah[4], al[4], bh[2], bl[2];
#pragma unroll
            for (int i = 0; i < 4; ++i) {
                ah[i] = *reinterpret_cast<const short8*>(&Ash[wm * 64 + i * 16 + l15][ks * 32 + quad * 8]);
                al[i] = *reinterpret_cast<const short8*>(&Asl[wm * 64 + i * 16 + l15][ks * 32 + quad * 8]);
            }
#pragma unroll
            for (int j = 0; j < 2; ++j) {
                bh[j] = *reinterpret_cast<const short8*>(&Bsh[wn * 32 + j * 16 + l15][ks * 32 + quad * 8]);
                bl[j] = *reinterpret_cast<const short8*>(&Bsl[wn * 32 + j * 16 + l15][ks * 32 + quad * 8]);
            }
#pragma unroll
            for (int i = 0; i < 4; ++i)
#pragma unroll
                for (int j = 0; j < 2; ++j) {
                    acc[i][j] = __builtin_amdgcn_mfma_f32_16x16x32_bf16(ah[i], bh[j], acc[i][j], 0, 0, 0);
                    acc[i][j] = __builtin_amdgcn_mfma_f32_16x16x32_bf16(ah[i], bl[j], acc[i][j], 0, 0, 0);
                    acc[i][j] = __builtin_amdgcn_mfma_f32_16x16x32_bf16(al[i], bh[j], acc[i][j], 0, 0, 0);
                }
        }
        __syncthreads();
    }
#pragma unroll
    for (int i = 0; i < 4; ++i) {
        const long grow = m0 + wm * 64 + i * 16 + quad * 4;
#pragma unroll
        for (int j = 0; j < 2; ++j) {
            const long gcol = n0 + wn * 32 + j * 16 + l15;
#pragma unroll
            for (int r = 0; r < 4; ++r)
                C[(grow + r) * 256 + gcol] = acc[i][j][r];
        }
    }
}

// ---------------------------------------------------------------- node stats: g, dn, per-dd |y| max
__global__ __launch_bounds__(256) void node_stats1(
        const float* __restrict__ xw1, const float* __restrict__ a1,
        const float* __restrict__ a22, float* __restrict__ g_out,
        float* __restrict__ dn, unsigned int* __restrict__ ddmax) {
    __shared__ float Mx[4][260];
    const int t = threadIdx.x;
    const int n0 = blockIdx.x * 64;
    const int r = t >> 2, q = t & 3;
    const long n = n0 + r;
    const float* xp = xw1 + n * 256 + q * 64;
    float vals[64];
    float facc = 0.f, dacc = 0.f;
#pragma unroll
    for (int i = 0; i < 16; ++i) {
        f32x4 v  = *reinterpret_cast<const f32x4*>(xp + i * 4);
        f32x4 b1 = *reinterpret_cast<const f32x4*>(a1 + q * 64 + i * 4);
        f32x4 b2 = *reinterpret_cast<const f32x4*>(a22 + q * 64 + i * 4);
#pragma unroll
        for (int k = 0; k < 4; ++k) {
            float lv = leakyf(v[k]);
            facc += lv * b1[k];
            dacc += lv * b2[k];
            vals[i * 4 + k] = v[k];
        }
    }
    facc += __shfl_xor(facc, 1); facc += __shfl_xor(facc, 2);
    dacc += __shfl_xor(dacc, 1); dacc += __shfl_xor(dacc, 2);
    const float g = satexpf(facc);
    if (q == 0) { dn[n] = dacc; g_out[n] = g; }
    float lm[64];
#pragma unroll
    for (int i = 0; i < 64; ++i) lm[i] = fabsf(vals[i] * g);
#pragma unroll
    for (int m = 4; m < 64; m <<= 1)
#pragma unroll
        for (int i = 0; i < 64; ++i) lm[i] = fmaxf(lm[i], __shfl_xor(lm[i], m));
    float gm = g;
#pragma unroll
    for (int m = 1; m < 64; m <<= 1) gm = fmaxf(gm, __shfl_xor(gm, m));
    const int wv = t >> 6, lane = t & 63;
    if (lane < 4) {
#pragma unroll
        for (int i = 0; i < 64; ++i) Mx[wv][lane * 64 + i] = lm[i];
    }
    if (lane == 0) Mx[wv][256] = gm;
    __syncthreads();
    if (t < 256) {
        float m = fmaxf(fmaxf(Mx[0][t], Mx[1][t]), fmaxf(Mx[2][t], Mx[3][t]));
        atomicMax(&ddmax[t], __float_as_uint(m));
    }
    if (t == 0) {  // index 256 (g); block has only 256 threads
        float m = fmaxf(fmaxf(Mx[0][256], Mx[1][256]), fmaxf(Mx[2][256], Mx[3][256]));
        atomicMax(&ddmax[256], __float_as_uint(m));
    }
}

// ---------------------------------------------------------------- quantize y -> yQ i8 [576,16384]
__global__ __launch_bounds__(256) void quantize_y(
        const float* __restrict__ xw1, const float* __restrict__ g_in,
        const unsigned int* __restrict__ ddmax, char* __restrict__ yQ) {
    __shared__ unsigned int Qh[257][16];
    __shared__ unsigned int Ql[257][16];
    const int t = threadIdx.x;
    const int n0 = blockIdx.x * 64;
    const int dd0 = (t >> 4) * 16;
    const int w = t & 15;
    const int r4 = w * 4;
    float s[16];
#pragma unroll
    for (int i = 0; i < 16; ++i)
        s[i] = 32512.f / __uint_as_float(ddmax[dd0 + i]);
    const float sg = 32512.f / __uint_as_float(ddmax[256]);
    unsigned int bh[16], bl[16];
#pragma unroll
    for (int i = 0; i < 16; ++i) { bh[i] = 0u; bl[i] = 0u; }
    unsigned int gh = 0u, gl = 0u;
#pragma unroll
    for (int rr = 0; rr < 4; ++rr) {
        const long n = n0 + r4 + rr;
        const float gg = g_in[n];
        const float* xp = xw1 + n * 256 + dd0;
#pragma unroll
        for (int c = 0; c < 4; ++c) {
            f32x4 v = *reinterpret_cast<const f32x4*>(xp + c * 4);
#pragma unroll
            for (int k = 0; k < 4; ++k) {
                const int i = c * 4 + k;
                int qv = __float2int_rn(v[k] * gg * s[i]);
                qv = max(-32639, min(32639, qv));
                const int qh = (qv + 128) >> 8;
                const int ql = qv - (qh << 8);
                bh[i] |= ((unsigned int)(qh & 255)) << (8 * rr);
                bl[i] |= ((unsigned int)(ql & 255)) << (8 * rr);
            }
        }
        if (t < 16) {
            int qv = __float2int_rn(gg * sg);
            qv = max(-32639, min(32639, qv));
            const int qh = (qv + 128) >> 8;
            const int ql = qv - (qh << 8);
            gh |= ((unsigned int)(qh & 255)) << (8 * rr);
            gl |= ((unsigned int)(ql & 255)) << (8 * rr);
        }
    }
#pragma unroll
    for (int i = 0; i < 16; ++i) { Qh[dd0 + i][w] = bh[i]; Ql[dd0 + i][w] = bl[i]; }
    if (t < 16) { Qh[256][t] = gh; Ql[256][t] = gl; }
    __syncthreads();
#pragma unroll
    for (int it = 0; it < 2; ++it) {
        const int dd = it * 256 + t;
        if (dd < 288) {
#pragma unroll
            for (int s2 = 0; s2 < 4; ++s2) {
                uint4v vh, vl;
                if (dd < 257) {
                    vh = *reinterpret_cast<const uint4v*>(&Qh[dd][s2 * 4]);
                    vl = *reinterpret_cast<const uint4v*>(&Ql[dd][s2 * 4]);
                } else {
#pragma unroll
                    for (int k = 0; k < 4; ++k) { vh[k] = 0u; vl[k] = 0u; }
                }
                *reinterpret_cast<uint4v*>(yQ + (long)dd * 16384 + n0 + s2 * 16) = vh;
                *reinterpret_cast<uint4v*>(yQ + (long)(288 + dd) * 16384 + n0 + s2 * 16) = vl;
            }
        }
    }
}

// ---------------------------------------------------------------- C1 GEMM, i8 MFMA, A expanded from bits in LDS
// BM=256 (j), BN=48 (dd), BK=128, z=8 (Ktile 2048), grid (16, 6, 8) = 768 blocks
// (3 blocks/CU, matching the ~51 KB LDS limit). Cp fp32 [8][4096][288].
__global__ __launch_bounds__(256) void gemm_c1_bits(
        const unsigned int* __restrict__ HbitsT, const char* __restrict__ Bb,
        float* __restrict__ Cp) {
    __shared__ char As[256][144];   // 36.9 KB
    __shared__ char Bsh[48][144];   // 6.9 KB
    __shared__ char Bsl[48][144];   // 6.9 KB
    const int t = threadIdx.x;
    const int wid = t >> 6, lane = t & 63;
    const int quad = lane >> 4, l15 = lane & 15;
    const long m0 = (long)blockIdx.x * 256;
    const long n0 = (long)blockIdx.y * 48;
    const long k0 = (long)blockIdx.z * 2048;
    float* Cz = Cp + (long)blockIdx.z * (4096L * 288);
    int4v acch[4][3], accl[4][3];
#pragma unroll
    for (int i = 0; i < 4; ++i)
#pragma unroll
        for (int j = 0; j < 3; ++j)
#pragma unroll
            for (int r = 0; r < 4; ++r) { acch[i][j][r] = 0; accl[i][j][r] = 0; }

    for (int kb = 0; kb < 2048; kb += 128) {
        // A: expand 128 H-bits of row (m0+t) into 128 i8
        {
            uint4v bv = *reinterpret_cast<const uint4v*>(
                    HbitsT + (m0 + t) * 512 + ((k0 + kb) >> 5));
#pragma unroll
            for (int w4 = 0; w4 < 4; ++w4) {
                const unsigned int u = bv[w4];
                uint4v e0, e1;
#pragma unroll
                for (int k = 0; k < 4; ++k) e0[k] = bits4_to_bytes(u >> (4 * k));
#pragma unroll
                for (int k = 0; k < 4; ++k) e1[k] = bits4_to_bytes(u >> (16 + 4 * k));
                *reinterpret_cast<uint4v*>(&As[t][w4 * 32]) = e0;
                *reinterpret_cast<uint4v*>(&As[t][w4 * 32 + 16]) = e1;
            }
        }
        // B: 48 rows x 128 B x 2 planes = 768 x 16B chunks.
        // (round-6 bugfix kept: explicit compare, NOT `cid & 383`)
#pragma unroll
        for (int it = 0; it < 3; ++it) {
            const int cid = t + it * 256;
            const int idx = (cid < 384) ? cid : cid - 384;
            const int row = idx >> 3, seg = (idx & 7) * 16;
            char* dst = (cid >= 384) ? &Bsl[row][seg] : &Bsh[row][seg];
            const long srow = (cid >= 384) ? (288 + n0 + row) : (n0 + row);
            *reinterpret_cast<uint4v*>(dst) =
                *reinterpret_cast<const uint4v*>(Bb + srow * 16384 + k0 + kb + seg);
        }
        __syncthreads();
#pragma unroll
        for (int ks = 0; ks < 2; ++ks) {
            int4v af[4], bh[3], bl[3];
#pragma unroll
            for (int i = 0; i < 4; ++i)
                af[i] = *reinterpret_cast<const int4v*>(
                        &As[wid * 64 + i * 16 + l15][ks * 64 + quad * 16]);
#pragma unroll
            for (int j = 0; j < 3; ++j) {
                bh[j] = *reinterpret_cast<const int4v*>(&Bsh[j * 16 + l15][ks * 64 + quad * 16]);
                bl[j] = *reinterpret_cast<const int4v*>(&Bsl[j * 16 + l15][ks * 64 + quad * 16]);
            }
#pragma unroll
            for (int i = 0; i < 4; ++i)
#pragma unroll
                for (int j = 0; j < 3; ++j) {
                    acch[i][j] = __builtin_amdgcn_mfma_i32_16x16x64_i8(af[i], bh[j], acch[i][j], 0, 0, 0);
                    accl[i][j] = __builtin_amdgcn_mfma_i32_16x16x64_i8(af[i], bl[j], accl[i][j], 0, 0, 0);
                }
        }
        __syncthreads();
    }
#pragma unroll
    for (int i = 0; i < 4; ++i) {
        const long grow = m0 + wid * 64 + i * 16 + quad * 4;
#pragma unroll
        for (int j = 0; j < 3; ++j) {
            const long gcol = n0 + j * 16 + l15;
#pragma unroll
            for (int r = 0; r < 4; ++r)
                Cz[(grow + r) * 288 + gcol] =
                    256.f * (float)acch[i][j][r] + (float)accl[i][j][r];
        }
    }
}

// ---------------------------------------------------------------- reduce split-K partials + reconstruct scale
__global__ __launch_bounds__(256) void reduce_C1(
        const float* __restrict__ C1p, const unsigned int* __restrict__ ddmax,
        float* __restrict__ C1) {
    const int i = blockIdx.x * 256 + threadIdx.x;   // < 4096*288
    const int dd = i % 288;
    float s = 0.f;
#pragma unroll
    for (int z = 0; z < 8; ++z) s += C1p[(long)z * 4096 * 288 + i];
    C1[i] = s * (__uint_as_float(ddmax[dd]) * (1.f / 32512.f));
}

// ---------------------------------------------------------------- G = f2@w2 split (+ GT bf16, c_j)
__global__ __launch_bounds__(256) void gemm_G(
        const float* __restrict__ C1, const short* __restrict__ w2Th,
        const short* __restrict__ w2Tl, const float* __restrict__ a21,
        short* __restrict__ GT, float* __restrict__ cat) {
    __shared__ short Ash[64][72];
    __shared__ short Asl[64][72];
    __shared__ short Bsh[64][72];
    __shared__ short Bsl[64][72];
    __shared__ float Gs[64][65];
    const int t = threadIdx.x;
    const int wid = t >> 6, lane = t & 63;
    const int wm = wid & 1, wn = wid >> 1;
    const int quad = lane >> 4, l15 = lane & 15;
    const long j0 = (long)blockIdx.x * 64;
    const long d0 = (long)blockIdx.y * 64;
    f32x4 acc[2][2];
#pragma unroll
    for (int i = 0; i < 2; ++i)
#pragma unroll
        for (int j = 0; j < 2; ++j)
#pragma unroll
            for (int r = 0; r < 4; ++r) acc[i][j][r] = 0.f;

    for (int kb = 0; kb < 256; kb += 64) {
#pragma unroll
        for (int it = 0; it < 2; ++it) {
            const int cid = t + it * 256;
            const int row = cid >> 3, c8 = (cid & 7) * 8;
            const float rd = fastrcp(C1[(j0 + row) * 288 + 256]);
            const float* ap = C1 + (j0 + row) * 288 + kb + c8;
            f32x4 v0 = *reinterpret_cast<const f32x4*>(ap);
            f32x4 v1 = *reinterpret_cast<const f32x4*>(ap + 4);
            short8 hi, lo;
#pragma unroll
            for (int k = 0; k < 4; ++k) {
                float f0 = leakyf(v0[k] * rd);
                float f1 = leakyf(v1[k] * rd);
                short h0 = f2b(f0); hi[k] = h0; lo[k] = f2b(f0 - b2f(h0));
                short h1 = f2b(f1); hi[4 + k] = h1; lo[4 + k] = f2b(f1 - b2f(h1));
            }
            *reinterpret_cast<short8*>(&Ash[row][c8]) = hi;
            *reinterpret_cast<short8*>(&Asl[row][c8]) = lo;
            *reinterpret_cast<short8*>(&Bsh[row][c8]) =
                *reinterpret_cast<const short8*>(w2Th + (d0 + row) * 256 + kb + c8);
            *reinterpret_cast<short8*>(&Bsl[row][c8]) =
                *reinterpret_cast<const short8*>(w2Tl + (d0 + row) * 256 + kb + c8);
        }
        __syncthreads();
#pragma unroll
        for (int ks = 0; ks < 2; ++ks) {
            short8 ah[2], al[2], bh[2], bl[2];
#pragma unroll
            for (int i = 0; i < 2; ++i) {
                ah[i] = *reinterpret_cast<const short8*>(&Ash[wm * 32 + i * 16 + l15][ks * 32 + quad * 8]);
                al[i] = *reinterpret_cast<const short8*>(&Asl[wm * 32 + i * 16 + l15][ks * 32 + quad * 8]);
            }
#pragma unroll
            for (int j = 0; j < 2; ++j) {
                bh[j] = *reinterpret_cast<const short8*>(&Bsh[wn * 32 + j * 16 + l15][ks * 32 + quad * 8]);
                bl[j] = *reinterpret_cast<const short8*>(&Bsl[wn * 32 + j * 16 + l15][ks * 32 + quad * 8]);
            }
#pragma unroll
            for (int i = 0; i < 2; ++i)
#pragma unroll
                for (int j = 0; j < 2; ++j) {
                    acc[i][j] = __builtin_amdgcn_mfma_f32_16x16x32_bf16(ah[i], bh[j], acc[i][j], 0, 0, 0);
                    acc[i][j] = __builtin_amdgcn_mfma_f32_16x16x32_bf16(ah[i], bl[j], acc[i][j], 0, 0, 0);
                    acc[i][j] = __builtin_amdgcn_mfma_f32_16x16x32_bf16(al[i], bh[j], acc[i][j], 0, 0, 0);
                }
        }
        __syncthreads();
    }
#pragma unroll
    for (int i = 0; i < 2; ++i)
#pragma unroll
        for (int j = 0; j < 2; ++j)
#pragma unroll
            for (int r = 0; r < 4; ++r)
                Gs[wm * 32 + i * 16 + quad * 4 + r][wn * 32 + j * 16 + l15] = acc[i][j][r];
    __syncthreads();
    {
        const int jl = t >> 2, q = t & 3;
        float cp = 0.f;
#pragma unroll
        for (int i = 0; i < 16; ++i) {
            const int d = q * 16 + i;
            cp += leakyf(Gs[jl][d]) * a21[d0 + d];
        }
        cp += __shfl_xor(cp, 1); cp += __shfl_xor(cp, 2);
        if (q == 0) atomicAdd(&cat[j0 + jl], cp);
    }
    {
        const int dl = t >> 2, q = t & 3;
        short8 pk0, pk1;
#pragma unroll
        for (int i = 0; i < 8; ++i) pk0[i] = f2b(Gs[q * 16 + i][dl]);
#pragma unroll
        for (int i = 0; i < 8; ++i) pk1[i] = f2b(Gs[q * 16 + 8 + i][dl]);
        short* gp = GT + (d0 + dl) * 4096 + j0 + q * 16;
        *reinterpret_cast<short8*>(gp) = pk0;
        *reinterpret_cast<short8*>(gp + 8) = pk1;
    }
}

// ---------------------------------------------------------------- FUSED edge weights + final GEMM
// BM=32, BN=256, BK=64, 512 threads (8 waves), grid 512 (2 blocks/CU: the
// round-5/7 versions ran 1 block/CU and had zero inter-block latency hiding).
__global__ __launch_bounds__(512) void fused_out(
        const unsigned int* __restrict__ Hbits, const float* __restrict__ cat,
        const float* __restrict__ dn, const short* __restrict__ GT,
        float* __restrict__ out) {
    __shared__ short As[32][72];    // 4.6 KB
    __shared__ short Bs[256][72];   // 36.9 KB
    __shared__ float rsS[32][16];
    __shared__ float rinvS[32];
    const int t = threadIdx.x;
    const int wid = t >> 6, lane = t & 63;
    const int wm = wid >> 2, wn = wid & 3;    // 2 m-groups x 4 n-groups
    const int quad = lane >> 4, l15 = lane & 15;
    const long m0 = (long)blockIdx.x * 32;
    const int r = t & 31, c4 = t >> 5;        // B-value role: row r, 4-col chunk c4
    const float drow = dn[m0 + r];
    const int bo = (c4 & 7) * 4;

    f32x4 acc[4];
#pragma unroll
    for (int j = 0; j < 4; ++j)
#pragma unroll
        for (int x = 0; x < 4; ++x) acc[j][x] = 0.f;
    float racc = 0.f;

    for (int kb = 0; kb < 4096; kb += 64) {
        // stage GT tile 256x64 (2048 x 16B chunks over 512 threads)
#pragma unroll
        for (int it = 0; it < 4; ++it) {
            const int cid = t + it * 512;
            const int row = cid >> 3, c8 = (cid & 7) * 8;
            *reinterpret_cast<short8*>(&Bs[row][c8]) =
                *reinterpret_cast<const short8*>(GT + row * 4096 + kb + c8);
        }
        // compute 4 B-values for (row r, cols kb + c4*4 .. +3)
        {
            const unsigned int w = Hbits[(m0 + r) * 128 + (kb >> 5) + (c4 >> 3)];
            f32x4 cv = *reinterpret_cast<const f32x4*>(cat + kb + c4 * 4);
            short4v pk;
#pragma unroll
            for (int k = 0; k < 4; ++k) {
                const float s = ((w >> (bo + k)) & 1u) ? satexpf(cv[k] + drow) : 0.f;
                const short sb = f2b(s);
                pk[k] = sb;
                racc += b2f(sb);
            }
            *reinterpret_cast<short4v*>(&As[r][c4 * 4]) = pk;
        }
        __syncthreads();
#pragma unroll
        for (int ks = 0; ks < 2; ++ks) {
            short8 af, bf[4];
            af = *reinterpret_cast<const short8*>(
                    &As[wm * 16 + l15][ks * 32 + quad * 8]);
#pragma unroll
            for (int j = 0; j < 4; ++j)
                bf[j] = *reinterpret_cast<const short8*>(
                        &Bs[wn * 64 + j * 16 + l15][ks * 32 + quad * 8]);
#pragma unroll
            for (int j = 0; j < 4; ++j)
                acc[j] = __builtin_amdgcn_mfma_f32_16x16x32_bf16(
                        af, bf[j], acc[j], 0, 0, 0);
        }
        __syncthreads();
    }
    rsS[r][c4] = racc;
    __syncthreads();
    if (t < 32) {
        float s = 0.f;
#pragma unroll
        for (int i = 0; i < 16; ++i) s += rsS[t][i];
        rinvS[t] = fastrcp(s);
    }
    __syncthreads();
#pragma unroll
    for (int j = 0; j < 4; ++j) {
        const long gcol = wn * 64 + j * 16 + l15;
#pragma unroll
        for (int x = 0; x < 4; ++x) {
            const int rl = wm * 16 + quad * 4 + x;
            out[(m0 + rl) * 256 + gcol] = leakyf(acc[j][x] * rinvS[rl]);
        }
    }
}

// ---------------------------------------------------------------- launch
extern "C" void kernel_launch(void* const* d_in, const int* in_sizes, int n_in,
                              void* d_out, int out_size, void* d_ws, size_t ws_size,
                              hipStream_t stream) {
    const float* x   = (const float*)d_in[0];
    const float* H   = (const float*)d_in[1];
    const float* w1  = (const float*)d_in[2];
    const float* w2  = (const float*)d_in[3];
    const float* a1  = (const float*)d_in[4];
    const float* a21 = (const float*)d_in[5];
    const float* a22 = (const float*)d_in[6];
    float* out = (float*)d_out;
    char* ws = (char*)d_ws;

    // region0: xw1 fp32 (16.8MB) then C1p fp32 [8][4096][288] (37.75MB) -- sequential reuse
    float* xw1   = (float*)(ws + 0);
    float* C1p   = (float*)(ws + 0);
    char*  yQ    = (char*)(ws + 67108864);                // [576,16384] i8 (9.44MB)
    float* dn    = (float*)(ws + 76546048);               // [16384]
    float* g     = (float*)(ws + 76611584);               // [16384]
    unsigned int* ddmax = (unsigned int*)(ws + 76677120); // [288]
    short* w1Th  = (short*)(ws + 76681216);
    short* w1Tl  = (short*)(ws + 76812288);
    short* w2Th  = (short*)(ws + 76943360);
    short* w2Tl  = (short*)(ws + 77074432);
    float* C1    = (float*)(ws + 77205504);               // [4096,288]
    short* GT    = (short*)(ws + 81924096);               // [256,4096] bf16
    float* cat   = (float*)(ws + 84021248);               // [4096]
    unsigned int* Hbits  = (unsigned int*)(ws + 84037632);// [16384,128] (8MB)
    unsigned int* HbitsT = (unsigned int*)(ws + 92426240);// [4096,512]  (8MB)

    hipMemsetAsync(ddmax, 0, 288 * sizeof(unsigned int), stream);
    hipMemsetAsync(cat, 0, 4096 * sizeof(float), stream);

    transpose_split2<<<dim3(4, 4, 2), 256, 0, stream>>>(
            w1, w1Th, w1Tl, w2, w2Th, w2Tl);
    transposeH_pack<<<dim3(256, 64), 256, 0, stream>>>(H, Hbits, HbitsT);

    gemm_xw1<<<dim3(128, 4), 256, 0, stream>>>(x, w1Th, w1Tl, xw1);
    node_stats1<<<dim3(256), 256, 0, stream>>>(xw1, a1, a22, g, dn, ddmax);
    quantize_y<<<dim3(256), 256, 0, stream>>>(xw1, g, ddmax, yQ);

    gemm_c1_bits<<<dim3(16, 6, 8), 256, 0, stream>>>(HbitsT, yQ, C1p);
    reduce_C1<<<dim3(4608), 256, 0, stream>>>(C1p, ddmax, C1);

    gemm_G<<<dim3(64, 4), 256, 0, stream>>>(C1, w2Th, w2Tl, a21, GT, cat);

    fused_out<<<dim3(512), 512, 0, stream>>>(Hbits, cat, dn, GT, out);
}

// Round 9
// 616.297 us; speedup vs baseline: 1.1074x; 1.0428x over previous
//
#include <hip/hip_runtime.h>

// HyperGAT layer, N=16384, E=4096, D=256 on gfx950.
//   xw1 = x@w1 (split-bf16 MFMA, ~fp32 accurate)
//   g_n = satexp(leaky(xw1)@a1), d_n = leaky(xw1)@a22
//   y = g*xw1 quantized to i16 (per-dd global scale), split qh/ql i8 planes
//   C1 = H^T @ [qh|ql]  (i8 MFMA; A expanded from j-major bit-pack in LDS)
//   f2 = leaky(C1/den);  G = f2@w2 (split);  c_j = leaky(G)@a21
//   out = leaky((B@G)/rowsum), B[n,j] = Hbit*satexp(c_j+d_n) on the fly,
//   j-split over 4 blocks (fp32 partials) + combine epilogue.

typedef __attribute__((ext_vector_type(8))) short short8;
typedef __attribute__((ext_vector_type(4))) short short4v;
typedef __attribute__((ext_vector_type(4))) float f32x4;
typedef __attribute__((ext_vector_type(4))) int int4v;
typedef __attribute__((ext_vector_type(4))) unsigned int uint4v;

__device__ __forceinline__ float leakyf(float v) { return v > 0.f ? v : 0.1f * v; }
__device__ __forceinline__ float fastrcp(float x) { return __builtin_amdgcn_rcpf(x); }

__device__ __forceinline__ float satexpf(float t) {
    float u = fminf(fmaxf(t * 0.25f, -30.f), 30.f);
    float p = __expf(u);
    float th = (p - 1.f) * fastrcp(p + 1.f);
    return __expf(8.f * th);
}

__device__ __forceinline__ short f2b(float v) {
    unsigned int x = __float_as_uint(v);
    x += 0x7fffu + ((x >> 16) & 1u);
    return (short)(x >> 16);
}
__device__ __forceinline__ float b2f(short s) {
    return __uint_as_float(((unsigned int)(unsigned short)s) << 16);
}
// 4 H-bits -> 4 i8 bytes (bit-deposit via magic multiply)
__device__ __forceinline__ unsigned int bits4_to_bytes(unsigned int s) {
    return ((s & 0xFu) * 0x00204081u) & 0x01010101u;
}

// ---------------------------------------------------------------- weight transposes (w1,w2) + hi/lo split
__global__ __launch_bounds__(256) void transpose_split2(
        const float* __restrict__ s0, short* __restrict__ dh0, short* __restrict__ dl0,
        const float* __restrict__ s1, short* __restrict__ dh1, short* __restrict__ dl1) {
    const float* src = blockIdx.z ? s1 : s0;
    short* dh = blockIdx.z ? dh1 : dh0;
    short* dl = blockIdx.z ? dl1 : dl0;
    __shared__ float Ts[64][65];
    const int t = threadIdx.x;
    const long r0 = (long)blockIdx.x * 64;
    const long c0 = (long)blockIdx.y * 64;
    {
        const int row = t >> 2, cc = (t & 3) * 16;
        const float* p = src + (r0 + row) * 256 + c0 + cc;
#pragma unroll
        for (int i = 0; i < 4; ++i) {
            f32x4 v = *reinterpret_cast<const f32x4*>(p + i * 4);
#pragma unroll
            for (int k = 0; k < 4; ++k) Ts[row][cc + i * 4 + k] = v[k];
        }
    }
    __syncthreads();
    {
        const int cl = t >> 2, ch = (t & 3) * 16;
        short8 h0, h1, l0, l1;
#pragma unroll
        for (int i = 0; i < 8; ++i) {
            float v = Ts[ch + i][cl];
            short h = f2b(v);
            h0[i] = h; l0[i] = f2b(v - b2f(h));
        }
#pragma unroll
        for (int i = 0; i < 8; ++i) {
            float v = Ts[ch + 8 + i][cl];
            short h = f2b(v);
            h1[i] = h; l1[i] = f2b(v - b2f(h));
        }
        short* qh = dh + (c0 + cl) * 256 + r0 + ch;
        short* ql = dl + (c0 + cl) * 256 + r0 + ch;
        *reinterpret_cast<short8*>(qh) = h0;
        *reinterpret_cast<short8*>(qh + 8) = h1;
        *reinterpret_cast<short8*>(ql) = l0;
        *reinterpret_cast<short8*>(ql + 8) = l1;
    }
}

// ---------------------------------------------------------------- H -> Hbits (n-major) + HbitsT (j-major); block(0,0) zeroes ddmax/cat
__global__ __launch_bounds__(256) void transposeH_pack(
        const float* __restrict__ H, unsigned int* __restrict__ Hbits,
        unsigned int* __restrict__ HbitsT, unsigned int* __restrict__ ddmax,
        float* __restrict__ cat) {
    __shared__ float Ts[64][65];
    const int t = threadIdx.x;
    const long r0 = (long)blockIdx.x * 64;   // n
    const long c0 = (long)blockIdx.y * 64;   // j
    if (blockIdx.x == 0 && blockIdx.y == 0) {   // fold the two memsets
        if (t < 256) ddmax[t] = 0u;
        if (t < 32) ddmax[256 + t] = 0u;
#pragma unroll
        for (int i = 0; i < 16; ++i) cat[t * 16 + i] = 0.f;
    }
    {
        const int row = t >> 2, cc = (t & 3) * 16;
        const float* p = H + (r0 + row) * 4096L + c0 + cc;
#pragma unroll
        for (int i = 0; i < 4; ++i) {
            f32x4 v = *reinterpret_cast<const f32x4*>(p + i * 4);
#pragma unroll
            for (int k = 0; k < 4; ++k) Ts[row][cc + i * 4 + k] = v[k];
        }
    }
    __syncthreads();
    if (t < 128) {           // Hbits: row n, bits over j
        const int nl = t >> 1, w = t & 1;
        unsigned int u = 0;
#pragma unroll
        for (int b = 0; b < 32; ++b)
            u |= (Ts[nl][w * 32 + b] != 0.f ? 1u : 0u) << b;
        Hbits[(r0 + nl) * 128 + (c0 >> 5) + w] = u;
    } else {                 // HbitsT: row j, bits over n
        const int t2 = t - 128;
        const int jl = t2 >> 1, w = t2 & 1;
        unsigned int u = 0;
#pragma unroll
        for (int b = 0; b < 32; ++b)
            u |= (Ts[w * 32 + b][jl] != 0.f ? 1u : 0u) << b;
        HbitsT[(c0 + jl) * 512 + (r0 >> 5) + w] = u;
    }
}

// ---------------------------------------------------------------- xw1 split GEMM (fp32-accurate)
__global__ __launch_bounds__(256) void gemm_xw1(
        const float* __restrict__ A, const short* __restrict__ Bh,
        const short* __restrict__ Bl, float* __restrict__ C) {
    __shared__ short Ash[128][72];
    __shared__ short Asl[128][72];
    __shared__ short Bsh[64][72];
    __shared__ short Bsl[64][72];
    const int t = threadIdx.x;
    const int wid = t >> 6, lane = t & 63;
    const int wm = wid & 1, wn = wid >> 1;
    const int quad = lane >> 4, l15 = lane & 15;
    const long m0 = (long)blockIdx.x * 128;
    const long n0 = (long)blockIdx.y * 64;
    f32x4 acc[4][2];
#pragma unroll
    for (int i = 0; i < 4; ++i)
#pragma unroll
        for (int j = 0; j < 2; ++j)
#pragma unroll
            for (int r = 0; r < 4; ++r) acc[i][j][r] = 0.f;

    for (int kb = 0; kb < 256; kb += 64) {
#pragma unroll
        for (int it = 0; it < 4; ++it) {
            const int cid = t + it * 256;
            const int row = cid >> 3, c8 = (cid & 7) * 8;
            const float* ap = A + (m0 + row) * 256 + kb + c8;
            f32x4 v0 = *reinterpret_cast<const f32x4*>(ap);
            f32x4 v1 = *reinterpret_cast<const f32x4*>(ap + 4);
            short8 hi, lo;
#pragma unroll
            for (int k = 0; k < 4; ++k) {
                short h0 = f2b(v0[k]); hi[k] = h0; lo[k] = f2b(v0[k] - b2f(h0));
                short h1 = f2b(v1[k]); hi[4 + k] = h1; lo[4 + k] = f2b(v1[k] - b2f(h1));
            }
            *reinterpret_cast<short8*>(&Ash[row][c8]) = hi;
            *reinterpret_cast<short8*>(&Asl[row][c8]) = lo;
        }
#pragma unroll
        for (int it = 0; it < 2; ++it) {
            const int cid = t + it * 256;
            const int row = cid >> 3, c8 = (cid & 7) * 8;
            *reinterpret_cast<short8*>(&Bsh[row][c8]) =
                *reinterpret_cast<const short8*>(Bh + (n0 + row) * 256 + kb + c8);
            *reinterpret_cast<short8*>(&Bsl[row][c8]) =
                *reinterpret_cast<const short8*>(Bl + (n0 + row) * 256 + kb + c8);
        }
        __syncthreads();
#pragma unroll
        for (int ks = 0; ks < 2; ++ks) {
            short8 ah[4], al[4], bh[2], bl[2];
#pragma unroll
            for (int i = 0; i < 4; ++i) {
                ah[i] = *reinterpret_cast<const short8*>(&Ash[wm * 64 + i * 16 + l15][ks * 32 + quad * 8]);
                al[i] = *reinterpret_cast<const short8*>(&Asl[wm * 64 + i * 16 + l15][ks * 32 + quad * 8]);
            }
#pragma unroll
            for (int j = 0; j < 2; ++j) {
                bh[j] = *reinterpret_cast<const short8*>(&Bsh[wn * 32 + j * 16 + l15][ks * 32 + quad * 8]);
                bl[j] = *reinterpret_cast<const short8*>(&Bsl[wn * 32 + j * 16 + l15][ks * 32 + quad * 8]);
            }
#pragma unroll
            for (int i = 0; i < 4; ++i)
#pragma unroll
                for (int j = 0; j < 2; ++j) {
                    acc[i][j] = __builtin_amdgcn_mfma_f32_16x16x32_bf16(ah[i], bh[j], acc[i][j], 0, 0, 0);
                    acc[i][j] = __builtin_amdgcn_mfma_f32_16x16x32_bf16(ah[i], bl[j], acc[i][j], 0, 0, 0);
                    acc[i][j] = __builtin_amdgcn_mfma_f32_16x16x32_bf16(al[i], bh[j], acc[i][j], 0, 0, 0);
                }
        }
        __syncthreads();
    }
#pragma unroll
    for (int i = 0; i < 4; ++i) {
        const long grow = m0 + wm * 64 + i * 16 + quad * 4;
#pragma unroll
        for (int j = 0; j < 2; ++j) {
            const long gcol = n0 + wn * 32 + j * 16 + l15;
#pragma unroll
            for (int r = 0; r < 4; ++r)
                C[(grow + r) * 256 + gcol] = acc[i][j][r];
        }
    }
}

// ---------------------------------------------------------------- node stats: g, dn, per-dd |y| max
__global__ __launch_bounds__(256) void node_stats1(
        const float* __restrict__ xw1, const float* __restrict__ a1,
        const float* __restrict__ a22, float* __restrict__ g_out,
        float* __restrict__ dn, unsigned int* __restrict__ ddmax) {
    __shared__ float Mx[4][260];
    const int t = threadIdx.x;
    const int n0 = blockIdx.x * 64;
    const int r = t >> 2, q = t & 3;
    const long n = n0 + r;
    const float* xp = xw1 + n * 256 + q * 64;
    float vals[64];
    float facc = 0.f, dacc = 0.f;
#pragma unroll
    for (int i = 0; i < 16; ++i) {
        f32x4 v  = *reinterpret_cast<const f32x4*>(xp + i * 4);
        f32x4 b1 = *reinterpret_cast<const f32x4*>(a1 + q * 64 + i * 4);
        f32x4 b2 = *reinterpret_cast<const f32x4*>(a22 + q * 64 + i * 4);
#pragma unroll
        for (int k = 0; k < 4; ++k) {
            float lv = leakyf(v[k]);
            facc += lv * b1[k];
            dacc += lv * b2[k];
            vals[i * 4 + k] = v[k];
        }
    }
    facc += __shfl_xor(facc, 1); facc += __shfl_xor(facc, 2);
    dacc += __shfl_xor(dacc, 1); dacc += __shfl_xor(dacc, 2);
    const float g = satexpf(facc);
    if (q == 0) { dn[n] = dacc; g_out[n] = g; }
    float lm[64];
#pragma unroll
    for (int i = 0; i < 64; ++i) lm[i] = fabsf(vals[i] * g);
#pragma unroll
    for (int m = 4; m < 64; m <<= 1)
#pragma unroll
        for (int i = 0; i < 64; ++i) lm[i] = fmaxf(lm[i], __shfl_xor(lm[i], m));
    float gm = g;
#pragma unroll
    for (int m = 1; m < 64; m <<= 1) gm = fmaxf(gm, __shfl_xor(gm, m));
    const int wv = t >> 6, lane = t & 63;
    if (lane < 4) {
#pragma unroll
        for (int i = 0; i < 64; ++i) Mx[wv][lane * 64 + i] = lm[i];
    }
    if (lane == 0) Mx[wv][256] = gm;
    __syncthreads();
    if (t < 256) {
        float m = fmaxf(fmaxf(Mx[0][t], Mx[1][t]), fmaxf(Mx[2][t], Mx[3][t]));
        atomicMax(&ddmax[t], __float_as_uint(m));
    }
    if (t == 0) {  // index 256 (g); block has only 256 threads
        float m = fmaxf(fmaxf(Mx[0][256], Mx[1][256]), fmaxf(Mx[2][256], Mx[3][256]));
        atomicMax(&ddmax[256], __float_as_uint(m));
    }
}

// ---------------------------------------------------------------- quantize y -> yQ i8 [576,16384]
__global__ __launch_bounds__(256) void quantize_y(
        const float* __restrict__ xw1, const float* __restrict__ g_in,
        const unsigned int* __restrict__ ddmax, char* __restrict__ yQ) {
    __shared__ unsigned int Qh[257][16];
    __shared__ unsigned int Ql[257][16];
    const int t = threadIdx.x;
    const int n0 = blockIdx.x * 64;
    const int dd0 = (t >> 4) * 16;
    const int w = t & 15;
    const int r4 = w * 4;
    float s[16];
#pragma unroll
    for (int i = 0; i < 16; ++i)
        s[i] = 32512.f / __uint_as_float(ddmax[dd0 + i]);
    const float sg = 32512.f / __uint_as_float(ddmax[256]);
    unsigned int bh[16], bl[16];
#pragma unroll
    for (int i = 0; i < 16; ++i) { bh[i] = 0u; bl[i] = 0u; }
    unsigned int gh = 0u, gl = 0u;
#pragma unroll
    for (int rr = 0; rr < 4; ++rr) {
        const long n = n0 + r4 + rr;
        const float gg = g_in[n];
        const float* xp = xw1 + n * 256 + dd0;
#pragma unroll
        for (int c = 0; c < 4; ++c) {
            f32x4 v = *reinterpret_cast<const f32x4*>(xp + c * 4);
#pragma unroll
            for (int k = 0; k < 4; ++k) {
                const int i = c * 4 + k;
                int qv = __float2int_rn(v[k] * gg * s[i]);
                qv = max(-32639, min(32639, qv));
                const int qh = (qv + 128) >> 8;
                const int ql = qv - (qh << 8);
                bh[i] |= ((unsigned int)(qh & 255)) << (8 * rr);
                bl[i] |= ((unsigned int)(ql & 255)) << (8 * rr);
            }
        }
        if (t < 16) {
            int qv = __float2int_rn(gg * sg);
            qv = max(-32639, min(32639, qv));
            const int qh = (qv + 128) >> 8;
            const int ql = qv - (qh << 8);
            gh |= ((unsigned int)(qh & 255)) << (8 * rr);
            gl |= ((unsigned int)(ql & 255)) << (8 * rr);
        }
    }
#pragma unroll
    for (int i = 0; i < 16; ++i) { Qh[dd0 + i][w] = bh[i]; Ql[dd0 + i][w] = bl[i]; }
    if (t < 16) { Qh[256][t] = gh; Ql[256][t] = gl; }
    __syncthreads();
#pragma unroll
    for (int it = 0; it < 2; ++it) {
        const int dd = it * 256 + t;
        if (dd < 288) {
#pragma unroll
            for (int s2 = 0; s2 < 4; ++s2) {
                uint4v vh, vl;
                if (dd < 257) {
                    vh = *reinterpret_cast<const uint4v*>(&Qh[dd][s2 * 4]);
                    vl = *reinterpret_cast<const uint4v*>(&Ql[dd][s2 * 4]);
                } else {
#pragma unroll
                    for (int k = 0; k < 4; ++k) { vh[k] = 0u; vl[k] = 0u; }
                }
                *reinterpret_cast<uint4v*>(yQ + (long)dd * 16384 + n0 + s2 * 16) = vh;
                *reinterpret_cast<uint4v*>(yQ + (long)(288 + dd) * 16384 + n0 + s2 * 16) = vl;
            }
        }
    }
}

// ---------------------------------------------------------------- C1 GEMM, i8 MFMA, A expanded from bits in LDS
// BM=256 (j), BN=48 (dd), BK=128, z=8 (Ktile 2048), grid (16, 6, 8) = 768 blocks.
__global__ __launch_bounds__(256) void gemm_c1_bits(
        const unsigned int* __restrict__ HbitsT, const char* __restrict__ Bb,
        float* __restrict__ Cp) {
    __shared__ char As[256][144];   // 36.9 KB
    __shared__ char Bsh[48][144];   // 6.9 KB
    __shared__ char Bsl[48][144];   // 6.9 KB
    const int t = threadIdx.x;
    const int wid = t >> 6, lane = t & 63;
    const int quad = lane >> 4, l15 = lane & 15;
    const long m0 = (long)blockIdx.x * 256;
    const long n0 = (long)blockIdx.y * 48;
    const long k0 = (long)blockIdx.z * 2048;
    float* Cz = Cp + (long)blockIdx.z * (4096L * 288);
    int4v acch[4][3], accl[4][3];
#pragma unroll
    for (int i = 0; i < 4; ++i)
#pragma unroll
        for (int j = 0; j < 3; ++j)
#pragma unroll
            for (int r = 0; r < 4; ++r) { acch[i][j][r] = 0; accl[i][j][r] = 0; }

    for (int kb = 0; kb < 2048; kb += 128) {
        // A: expand 128 H-bits of row (m0+t) into 128 i8
        {
            uint4v bv = *reinterpret_cast<const uint4v*>(
                    HbitsT + (m0 + t) * 512 + ((k0 + kb) >> 5));
#pragma unroll
            for (int w4 = 0; w4 < 4; ++w4) {
                const unsigned int u = bv[w4];
                uint4v e0, e1;
#pragma unroll
                for (int k = 0; k < 4; ++k) e0[k] = bits4_to_bytes(u >> (4 * k));
#pragma unroll
                for (int k = 0; k < 4; ++k) e1[k] = bits4_to_bytes(u >> (16 + 4 * k));
                *reinterpret_cast<uint4v*>(&As[t][w4 * 32]) = e0;
                *reinterpret_cast<uint4v*>(&As[t][w4 * 32 + 16]) = e1;
            }
        }
        // B: 48 rows x 128 B x 2 planes = 768 x 16B chunks.
        // (round-6 bugfix kept: explicit compare, NOT `cid & 383`)
#pragma unroll
        for (int it = 0; it < 3; ++it) {
            const int cid = t + it * 256;
            const int idx = (cid < 384) ? cid : cid - 384;
            const int row = idx >> 3, seg = (idx & 7) * 16;
            char* dst = (cid >= 384) ? &Bsl[row][seg] : &Bsh[row][seg];
            const long srow = (cid >= 384) ? (288 + n0 + row) : (n0 + row);
            *reinterpret_cast<uint4v*>(dst) =
                *reinterpret_cast<const uint4v*>(Bb + srow * 16384 + k0 + kb + seg);
        }
        __syncthreads();
#pragma unroll
        for (int ks = 0; ks < 2; ++ks) {
            int4v af[4], bh[3], bl[3];
#pragma unroll
            for (int i = 0; i < 4; ++i)
                af[i] = *reinterpret_cast<const int4v*>(
                        &As[wid * 64 + i * 16 + l15][ks * 64 + quad * 16]);
#pragma unroll
            for (int j = 0; j < 3; ++j) {
                bh[j] = *reinterpret_cast<const int4v*>(&Bsh[j * 16 + l15][ks * 64 + quad * 16]);
                bl[j] = *reinterpret_cast<const int4v*>(&Bsl[j * 16 + l15][ks * 64 + quad * 16]);
            }
#pragma unroll
            for (int i = 0; i < 4; ++i)
#pragma unroll
                for (int j = 0; j < 3; ++j) {
                    acch[i][j] = __builtin_amdgcn_mfma_i32_16x16x64_i8(af[i], bh[j], acch[i][j], 0, 0, 0);
                    accl[i][j] = __builtin_amdgcn_mfma_i32_16x16x64_i8(af[i], bl[j], accl[i][j], 0, 0, 0);
                }
        }
        __syncthreads();
    }
#pragma unroll
    for (int i = 0; i < 4; ++i) {
        const long grow = m0 + wid * 64 + i * 16 + quad * 4;
#pragma unroll
        for (int j = 0; j < 3; ++j) {
            const long gcol = n0 + j * 16 + l15;
#pragma unroll
            for (int r = 0; r < 4; ++r)
                Cz[(grow + r) * 288 + gcol] =
                    256.f * (float)acch[i][j][r] + (float)accl[i][j][r];
        }
    }
}

// ---------------------------------------------------------------- reduce split-K partials + reconstruct scale
__global__ __launch_bounds__(256) void reduce_C1(
        const float* __restrict__ C1p, const unsigned int* __restrict__ ddmax,
        float* __restrict__ C1) {
    const int i = blockIdx.x * 256 + threadIdx.x;   // < 4096*288
    const int dd = i % 288;
    float s = 0.f;
#pragma unroll
    for (int z = 0; z < 8; ++z) s += C1p[(long)z * 4096 * 288 + i];
    C1[i] = s * (__uint_as_float(ddmax[dd]) * (1.f / 32512.f));
}

// ---------------------------------------------------------------- G = f2@w2 split (+ GT bf16, c_j)
__global__ __launch_bounds__(256) void gemm_G(
        const float* __restrict__ C1, const short* __restrict__ w2Th,
        const short* __restrict__ w2Tl, const float* __restrict__ a21,
        short* __restrict__ GT, float* __restrict__ cat) {
    __shared__ short Ash[64][72];
    __shared__ short Asl[64][72];
    __shared__ short Bsh[64][72];
    __shared__ short Bsl[64][72];
    __shared__ float Gs[64][65];
    const int t = threadIdx.x;
    const int wid = t >> 6, lane = t & 63;
    const int wm = wid & 1, wn = wid >> 1;
    const int quad = lane >> 4, l15 = lane & 15;
    const long j0 = (long)blockIdx.x * 64;
    const long d0 = (long)blockIdx.y * 64;
    f32x4 acc[2][2];
#pragma unroll
    for (int i = 0; i < 2; ++i)
#pragma unroll
        for (int j = 0; j < 2; ++j)
#pragma unroll
            for (int r = 0; r < 4; ++r) acc[i][j][r] = 0.f;

    for (int kb = 0; kb < 256; kb += 64) {
#pragma unroll
        for (int it = 0; it < 2; ++it) {
            const int cid = t + it * 256;
            const int row = cid >> 3, c8 = (cid & 7) * 8;
            const float rd = fastrcp(C1[(j0 + row) * 288 + 256]);
            const float* ap = C1 + (j0 + row) * 288 + kb + c8;
            f32x4 v0 = *reinterpret_cast<const f32x4*>(ap);
            f32x4 v1 = *reinterpret_cast<const f32x4*>(ap + 4);
            short8 hi, lo;
#pragma unroll
            for (int k = 0; k < 4; ++k) {
                float f0 = leakyf(v0[k] * rd);
                float f1 = leakyf(v1[k] * rd);
                short h0 = f2b(f0); hi[k] = h0; lo[k] = f2b(f0 - b2f(h0));
                short h1 = f2b(f1); hi[4 + k] = h1; lo[4 + k] = f2b(f1 - b2f(h1));
            }
            *reinterpret_cast<short8*>(&Ash[row][c8]) = hi;
            *reinterpret_cast<short8*>(&Asl[row][c8]) = lo;
            *reinterpret_cast<short8*>(&Bsh[row][c8]) =
                *reinterpret_cast<const short8*>(w2Th + (d0 + row) * 256 + kb + c8);
            *reinterpret_cast<short8*>(&Bsl[row][c8]) =
                *reinterpret_cast<const short8*>(w2Tl + (d0 + row) * 256 + kb + c8);
        }
        __syncthreads();
#pragma unroll
        for (int ks = 0; ks < 2; ++ks) {
            short8 ah[2], al[2], bh[2], bl[2];
#pragma unroll
            for (int i = 0; i < 2; ++i) {
                ah[i] = *reinterpret_cast<const short8*>(&Ash[wm * 32 + i * 16 + l15][ks * 32 + quad * 8]);
                al[i] = *reinterpret_cast<const short8*>(&Asl[wm * 32 + i * 16 + l15][ks * 32 + quad * 8]);
            }
#pragma unroll
            for (int j = 0; j < 2; ++j) {
                bh[j] = *reinterpret_cast<const short8*>(&Bsh[wn * 32 + j * 16 + l15][ks * 32 + quad * 8]);
                bl[j] = *reinterpret_cast<const short8*>(&Bsl[wn * 32 + j * 16 + l15][ks * 32 + quad * 8]);
            }
#pragma unroll
            for (int i = 0; i < 2; ++i)
#pragma unroll
                for (int j = 0; j < 2; ++j) {
                    acc[i][j] = __builtin_amdgcn_mfma_f32_16x16x32_bf16(ah[i], bh[j], acc[i][j], 0, 0, 0);
                    acc[i][j] = __builtin_amdgcn_mfma_f32_16x16x32_bf16(ah[i], bl[j], acc[i][j], 0, 0, 0);
                    acc[i][j] = __builtin_amdgcn_mfma_f32_16x16x32_bf16(al[i], bh[j], acc[i][j], 0, 0, 0);
                }
        }
        __syncthreads();
    }
#pragma unroll
    for (int i = 0; i < 2; ++i)
#pragma unroll
        for (int j = 0; j < 2; ++j)
#pragma unroll
            for (int r = 0; r < 4; ++r)
                Gs[wm * 32 + i * 16 + quad * 4 + r][wn * 32 + j * 16 + l15] = acc[i][j][r];
    __syncthreads();
    {
        const int jl = t >> 2, q = t & 3;
        float cp = 0.f;
#pragma unroll
        for (int i = 0; i < 16; ++i) {
            const int d = q * 16 + i;
            cp += leakyf(Gs[jl][d]) * a21[d0 + d];
        }
        cp += __shfl_xor(cp, 1); cp += __shfl_xor(cp, 2);
        if (q == 0) atomicAdd(&cat[j0 + jl], cp);
    }
    {
        const int dl = t >> 2, q = t & 3;
        short8 pk0, pk1;
#pragma unroll
        for (int i = 0; i < 8; ++i) pk0[i] = f2b(Gs[q * 16 + i][dl]);
#pragma unroll
        for (int i = 0; i < 8; ++i) pk1[i] = f2b(Gs[q * 16 + 8 + i][dl]);
        short* gp = GT + (d0 + dl) * 4096 + j0 + q * 16;
        *reinterpret_cast<short8*>(gp) = pk0;
        *reinterpret_cast<short8*>(gp + 8) = pk1;
    }
}

// ---------------------------------------------------------------- FUSED edge weights + final GEMM, j-split
// BM=64, BN=256, BK=64, Ktile=1024 (z=4), 512 threads, grid (256,4) = 1024 blocks.
// Writes fp32 out-partials + rowsum-partials; combine_out applies leaky(/rowsum).
__global__ __launch_bounds__(512, 4) void fused_out_split(
        const unsigned int* __restrict__ Hbits, const float* __restrict__ cat,
        const float* __restrict__ dn, const short* __restrict__ GT,
        float* __restrict__ outP, float* __restrict__ rsP) {
    __shared__ short As[64][72];    // 9.2 KB
    __shared__ short Bs[256][72];   // 36.9 KB
    __shared__ float rsS[64][8];
    const int t = threadIdx.x;
    const int wid = t >> 6, lane = t & 63;
    const int wm = wid >> 2, wn = wid & 3;    // 2 m-groups x 4 n-groups
    const int quad = lane >> 4, l15 = lane & 15;
    const long m0 = (long)blockIdx.x * 64;
    const int z = blockIdx.y;
    const int kbase = z * 1024;
    const int r = t & 63, c8 = t >> 6;        // B-value role: row r, 8-col chunk c8
    const float drow = dn[m0 + r];
    const int bo = (c8 & 3) * 8;

    f32x4 acc[2][4];
#pragma unroll
    for (int i = 0; i < 2; ++i)
#pragma unroll
        for (int j = 0; j < 4; ++j)
#pragma unroll
            for (int x = 0; x < 4; ++x) acc[i][j][x] = 0.f;
    float racc = 0.f;

    for (int kk = 0; kk < 1024; kk += 64) {
        const int kb = kbase + kk;
        // stage GT tile 256x64 (2048 x 16B chunks over 512 threads)
#pragma unroll
        for (int it = 0; it < 4; ++it) {
            const int cid = t + it * 512;
            const int row = cid >> 3, cc = (cid & 7) * 8;
            *reinterpret_cast<short8*>(&Bs[row][cc]) =
                *reinterpret_cast<const short8*>(GT + row * 4096 + kb + cc);
        }
        // compute 8 B-values for (row r, cols kb + c8*8 .. +7)
        {
            const unsigned int w = Hbits[(m0 + r) * 128 + (kb >> 5) + (c8 >> 2)];
            f32x4 cv0 = *reinterpret_cast<const f32x4*>(cat + kb + c8 * 8);
            f32x4 cv1 = *reinterpret_cast<const f32x4*>(cat + kb + c8 * 8 + 4);
            short8 pk;
#pragma unroll
            for (int k = 0; k < 8; ++k) {
                const float cvk = (k < 4) ? cv0[k & 3] : cv1[k & 3];
                const float s = ((w >> (bo + k)) & 1u) ? satexpf(cvk + drow) : 0.f;
                const short sb = f2b(s);
                pk[k] = sb;
                racc += b2f(sb);
            }
            *reinterpret_cast<short8*>(&As[r][c8 * 8]) = pk;
        }
        __syncthreads();
#pragma unroll
        for (int ks = 0; ks < 2; ++ks) {
            short8 af[2], bf[4];
#pragma unroll
            for (int i = 0; i < 2; ++i)
                af[i] = *reinterpret_cast<const short8*>(
                        &As[wm * 32 + i * 16 + l15][ks * 32 + quad * 8]);
#pragma unroll
            for (int j = 0; j < 4; ++j)
                bf[j] = *reinterpret_cast<const short8*>(
                        &Bs[wn * 64 + j * 16 + l15][ks * 32 + quad * 8]);
#pragma unroll
            for (int i = 0; i < 2; ++i)
#pragma unroll
                for (int j = 0; j < 4; ++j)
                    acc[i][j] = __builtin_amdgcn_mfma_f32_16x16x32_bf16(
                            af[i], bf[j], acc[i][j], 0, 0, 0);
        }
        __syncthreads();
    }
    rsS[r][c8] = racc;
    __syncthreads();
    if (t < 64) {
        float s = 0.f;
#pragma unroll
        for (int i = 0; i < 8; ++i) s += rsS[t][i];
        rsP[z * 16384 + m0 + t] = s;
    }
    float* op = outP + (long)z * (16384L * 256);
#pragma unroll
    for (int i = 0; i < 2; ++i) {
#pragma unroll
        for (int j = 0; j < 4; ++j) {
            const long gcol = wn * 64 + j * 16 + l15;
#pragma unroll
            for (int x = 0; x < 4; ++x) {
                const long grow = m0 + wm * 32 + i * 16 + quad * 4 + x;
                op[grow * 256 + gcol] = acc[i][j][x];
            }
        }
    }
}

// ---------------------------------------------------------------- combine: out = leaky(sum_z outP / sum_z rsP)
__global__ __launch_bounds__(256) void combine_out(
        const float* __restrict__ outP, const float* __restrict__ rsP,
        float* __restrict__ out) {
    const long i = ((long)blockIdx.x * 256 + threadIdx.x) * 4;  // grid 4096
    const long n = i >> 8;
    f32x4 s = *reinterpret_cast<const f32x4*>(outP + i);
#pragma unroll
    for (int z = 1; z < 4; ++z) {
        f32x4 v = *reinterpret_cast<const f32x4*>(outP + (long)z * (16384L * 256) + i);
#pragma unroll
        for (int k = 0; k < 4; ++k) s[k] += v[k];
    }
    const float rinv = fastrcp(rsP[n] + rsP[16384 + n] + rsP[32768 + n] + rsP[49152 + n]);
    f32x4 o;
#pragma unroll
    for (int k = 0; k < 4; ++k) o[k] = leakyf(s[k] * rinv);
    *reinterpret_cast<f32x4*>(out + i) = o;
}

// ---------------------------------------------------------------- launch
extern "C" void kernel_launch(void* const* d_in, const int* in_sizes, int n_in,
                              void* d_out, int out_size, void* d_ws, size_t ws_size,
                              hipStream_t stream) {
    const float* x   = (const float*)d_in[0];
    const float* H   = (const float*)d_in[1];
    const float* w1  = (const float*)d_in[2];
    const float* w2  = (const float*)d_in[3];
    const float* a1  = (const float*)d_in[4];
    const float* a21 = (const float*)d_in[5];
    const float* a22 = (const float*)d_in[6];
    float* out = (float*)d_out;
    char* ws = (char*)d_ws;

    // region0: xw1 fp32 (16.8MB) then C1p fp32 [8][4096][288] (37.75MB) -- sequential reuse
    float* xw1   = (float*)(ws + 0);
    float* C1p   = (float*)(ws + 0);
    char*  yQ    = (char*)(ws + 67108864);                // [576,16384] i8 (9.44MB)
    float* dn    = (float*)(ws + 76546048);               // [16384]
    float* g     = (float*)(ws + 76611584);               // [16384]
    unsigned int* ddmax = (unsigned int*)(ws + 76677120); // [288]
    short* w1Th  = (short*)(ws + 76681216);
    short* w1Tl  = (short*)(ws + 76812288);
    short* w2Th  = (short*)(ws + 76943360);
    short* w2Tl  = (short*)(ws + 77074432);
    float* C1    = (float*)(ws + 77205504);               // [4096,288]
    short* GT    = (short*)(ws + 81924096);               // [256,4096] bf16
    float* cat   = (float*)(ws + 84021248);               // [4096]
    unsigned int* Hbits  = (unsigned int*)(ws + 84037632);// [16384,128] (8MB)
    unsigned int* HbitsT = (unsigned int*)(ws + 92426240);// [4096,512]  (8MB)
    float* outP  = (float*)(ws + 134217728);              // [4][16384,256] (67.1MB)
    float* rsP   = (float*)(ws + 201326592);              // [4][16384]

    transpose_split2<<<dim3(4, 4, 2), 256, 0, stream>>>(
            w1, w1Th, w1Tl, w2, w2Th, w2Tl);
    transposeH_pack<<<dim3(256, 64), 256, 0, stream>>>(H, Hbits, HbitsT, ddmax, cat);

    gemm_xw1<<<dim3(128, 4), 256, 0, stream>>>(x, w1Th, w1Tl, xw1);
    node_stats1<<<dim3(256), 256, 0, stream>>>(xw1, a1, a22, g, dn, ddmax);
    quantize_y<<<dim3(256), 256, 0, stream>>>(xw1, g, ddmax, yQ);

    gemm_c1_bits<<<dim3(16, 6, 8), 256, 0, stream>>>(HbitsT, yQ, C1p);
    reduce_C1<<<dim3(4608), 256, 0, stream>>>(C1p, ddmax, C1);

    gemm_G<<<dim3(64, 4), 256, 0, stream>>>(C1, w2Th, w2Tl, a21, GT, cat);

    fused_out_split<<<dim3(256, 4), 512, 0, stream>>>(Hbits, cat, dn, GT, outP, rsP);
    combine_out<<<dim3(4096), 256, 0, stream>>>(outP, rsP, out);
}

// Round 10
// 611.141 us; speedup vs baseline: 1.1168x; 1.0084x over previous
//
#include <hip/hip_runtime.h>

// HyperGAT layer, N=16384, E=4096, D=256 on gfx950.
//   xw1 = x@w1 (split-bf16 MFMA, ~fp32 accurate)
//   g_n = satexp(leaky(xw1)@a1), d_n = leaky(xw1)@a22
//   y = g*xw1 quantized to i16 (per-dd global scale), split qh/ql i8 planes
//   C1 = H^T @ [qh|ql]  (i8 MFMA; A-fragments expanded from bit-pack IN REGISTERS)
//   f2 = leaky(C1/den);  G = f2@w2 (split);  c_j = leaky(G)@a21
//   out = leaky((B@G)/rowsum), B[n,j] = Hbit*satexp(c_j+d_n) on the fly,
//   j-split over 4 blocks (fp32 partials) + combine epilogue.

typedef __attribute__((ext_vector_type(8))) short short8;
typedef __attribute__((ext_vector_type(4))) short short4v;
typedef __attribute__((ext_vector_type(4))) float f32x4;
typedef __attribute__((ext_vector_type(4))) int int4v;
typedef __attribute__((ext_vector_type(4))) unsigned int uint4v;

__device__ __forceinline__ float leakyf(float v) { return v > 0.f ? v : 0.1f * v; }
__device__ __forceinline__ float fastrcp(float x) { return __builtin_amdgcn_rcpf(x); }

__device__ __forceinline__ float satexpf(float t) {
    float u = fminf(fmaxf(t * 0.25f, -30.f), 30.f);
    float p = __expf(u);
    float th = (p - 1.f) * fastrcp(p + 1.f);
    return __expf(8.f * th);
}

__device__ __forceinline__ short f2b(float v) {
    unsigned int x = __float_as_uint(v);
    x += 0x7fffu + ((x >> 16) & 1u);
    return (short)(x >> 16);
}
__device__ __forceinline__ float b2f(short s) {
    return __uint_as_float(((unsigned int)(unsigned short)s) << 16);
}
// 4 H-bits -> 4 i8 bytes (bit-deposit via magic multiply)
__device__ __forceinline__ unsigned int bits4_to_bytes(unsigned int s) {
    return ((s & 0xFu) * 0x00204081u) & 0x01010101u;
}

// ---------------------------------------------------------------- weight transposes (w1,w2) + hi/lo split
__global__ __launch_bounds__(256) void transpose_split2(
        const float* __restrict__ s0, short* __restrict__ dh0, short* __restrict__ dl0,
        const float* __restrict__ s1, short* __restrict__ dh1, short* __restrict__ dl1) {
    const float* src = blockIdx.z ? s1 : s0;
    short* dh = blockIdx.z ? dh1 : dh0;
    short* dl = blockIdx.z ? dl1 : dl0;
    __shared__ float Ts[64][65];
    const int t = threadIdx.x;
    const long r0 = (long)blockIdx.x * 64;
    const long c0 = (long)blockIdx.y * 64;
    {
        const int row = t >> 2, cc = (t & 3) * 16;
        const float* p = src + (r0 + row) * 256 + c0 + cc;
#pragma unroll
        for (int i = 0; i < 4; ++i) {
            f32x4 v = *reinterpret_cast<const f32x4*>(p + i * 4);
#pragma unroll
            for (int k = 0; k < 4; ++k) Ts[row][cc + i * 4 + k] = v[k];
        }
    }
    __syncthreads();
    {
        const int cl = t >> 2, ch = (t & 3) * 16;
        short8 h0, h1, l0, l1;
#pragma unroll
        for (int i = 0; i < 8; ++i) {
            float v = Ts[ch + i][cl];
            short h = f2b(v);
            h0[i] = h; l0[i] = f2b(v - b2f(h));
        }
#pragma unroll
        for (int i = 0; i < 8; ++i) {
            float v = Ts[ch + 8 + i][cl];
            short h = f2b(v);
            h1[i] = h; l1[i] = f2b(v - b2f(h));
        }
        short* qh = dh + (c0 + cl) * 256 + r0 + ch;
        short* ql = dl + (c0 + cl) * 256 + r0 + ch;
        *reinterpret_cast<short8*>(qh) = h0;
        *reinterpret_cast<short8*>(qh + 8) = h1;
        *reinterpret_cast<short8*>(ql) = l0;
        *reinterpret_cast<short8*>(ql + 8) = l1;
    }
}

// ---------------------------------------------------------------- H -> Hbits (n-major) + HbitsT (j-major); block(0,0) zeroes ddmax/cat
__global__ __launch_bounds__(256) void transposeH_pack(
        const float* __restrict__ H, unsigned int* __restrict__ Hbits,
        unsigned int* __restrict__ HbitsT, unsigned int* __restrict__ ddmax,
        float* __restrict__ cat) {
    __shared__ float Ts[64][65];
    const int t = threadIdx.x;
    const long r0 = (long)blockIdx.x * 64;   // n
    const long c0 = (long)blockIdx.y * 64;   // j
    if (blockIdx.x == 0 && blockIdx.y == 0) {   // fold the two memsets
        if (t < 256) ddmax[t] = 0u;
        if (t < 32) ddmax[256 + t] = 0u;
#pragma unroll
        for (int i = 0; i < 16; ++i) cat[t * 16 + i] = 0.f;
    }
    {
        const int row = t >> 2, cc = (t & 3) * 16;
        const float* p = H + (r0 + row) * 4096L + c0 + cc;
#pragma unroll
        for (int i = 0; i < 4; ++i) {
            f32x4 v = *reinterpret_cast<const f32x4*>(p + i * 4);
#pragma unroll
            for (int k = 0; k < 4; ++k) Ts[row][cc + i * 4 + k] = v[k];
        }
    }
    __syncthreads();
    if (t < 128) {           // Hbits: row n, bits over j
        const int nl = t >> 1, w = t & 1;
        unsigned int u = 0;
#pragma unroll
        for (int b = 0; b < 32; ++b)
            u |= (Ts[nl][w * 32 + b] != 0.f ? 1u : 0u) << b;
        Hbits[(r0 + nl) * 128 + (c0 >> 5) + w] = u;
    } else {                 // HbitsT: row j, bits over n
        const int t2 = t - 128;
        const int jl = t2 >> 1, w = t2 & 1;
        unsigned int u = 0;
#pragma unroll
        for (int b = 0; b < 32; ++b)
            u |= (Ts[w * 32 + b][jl] != 0.f ? 1u : 0u) << b;
        HbitsT[(c0 + jl) * 512 + (r0 >> 5) + w] = u;
    }
}

// ---------------------------------------------------------------- xw1 split GEMM (fp32-accurate)
__global__ __launch_bounds__(256) void gemm_xw1(
        const float* __restrict__ A, const short* __restrict__ Bh,
        const short* __restrict__ Bl, float* __restrict__ C) {
    __shared__ short Ash[128][72];
    __shared__ short Asl[128][72];
    __shared__ short Bsh[64][72];
    __shared__ short Bsl[64][72];
    const int t = threadIdx.x;
    const int wid = t >> 6, lane = t & 63;
    const int wm = wid & 1, wn = wid >> 1;
    const int quad = lane >> 4, l15 = lane & 15;
    const long m0 = (long)blockIdx.x * 128;
    const long n0 = (long)blockIdx.y * 64;
    f32x4 acc[4][2];
#pragma unroll
    for (int i = 0; i < 4; ++i)
#pragma unroll
        for (int j = 0; j < 2; ++j)
#pragma unroll
            for (int r = 0; r < 4; ++r) acc[i][j][r] = 0.f;

    for (int kb = 0; kb < 256; kb += 64) {
#pragma unroll
        for (int it = 0; it < 4; ++it) {
            const int cid = t + it * 256;
            const int row = cid >> 3, c8 = (cid & 7) * 8;
            const float* ap = A + (m0 + row) * 256 + kb + c8;
            f32x4 v0 = *reinterpret_cast<const f32x4*>(ap);
            f32x4 v1 = *reinterpret_cast<const f32x4*>(ap + 4);
            short8 hi, lo;
#pragma unroll
            for (int k = 0; k < 4; ++k) {
                short h0 = f2b(v0[k]); hi[k] = h0; lo[k] = f2b(v0[k] - b2f(h0));
                short h1 = f2b(v1[k]); hi[4 + k] = h1; lo[4 + k] = f2b(v1[k] - b2f(h1));
            }
            *reinterpret_cast<short8*>(&Ash[row][c8]) = hi;
            *reinterpret_cast<short8*>(&Asl[row][c8]) = lo;
        }
#pragma unroll
        for (int it = 0; it < 2; ++it) {
            const int cid = t + it * 256;
            const int row = cid >> 3, c8 = (cid & 7) * 8;
            *reinterpret_cast<short8*>(&Bsh[row][c8]) =
                *reinterpret_cast<const short8*>(Bh + (n0 + row) * 256 + kb + c8);
            *reinterpret_cast<short8*>(&Bsl[row][c8]) =
                *reinterpret_cast<const short8*>(Bl + (n0 + row) * 256 + kb + c8);
        }
        __syncthreads();
#pragma unroll
        for (int ks = 0; ks < 2; ++ks) {
            short8 ah[4], al[4], bh[2], bl[2];
#pragma unroll
            for (int i = 0; i < 4; ++i) {
                ah[i] = *reinterpret_cast<const short8*>(&Ash[wm * 64 + i * 16 + l15][ks * 32 + quad * 8]);
                al[i] = *reinterpret_cast<const short8*>(&Asl[wm * 64 + i * 16 + l15][ks * 32 + quad * 8]);
            }
#pragma unroll
            for (int j = 0; j < 2; ++j) {
                bh[j] = *reinterpret_cast<const short8*>(&Bsh[wn * 32 + j * 16 + l15][ks * 32 + quad * 8]);
                bl[j] = *reinterpret_cast<const short8*>(&Bsl[wn * 32 + j * 16 + l15][ks * 32 + quad * 8]);
            }
#pragma unroll
            for (int i = 0; i < 4; ++i)
#pragma unroll
                for (int j = 0; j < 2; ++j) {
                    acc[i][j] = __builtin_amdgcn_mfma_f32_16x16x32_bf16(ah[i], bh[j], acc[i][j], 0, 0, 0);
                    acc[i][j] = __builtin_amdgcn_mfma_f32_16x16x32_bf16(ah[i], bl[j], acc[i][j], 0, 0, 0);
                    acc[i][j] = __builtin_amdgcn_mfma_f32_16x16x32_bf16(al[i], bh[j], acc[i][j], 0, 0, 0);
                }
        }
        __syncthreads();
    }
#pragma unroll
    for (int i = 0; i < 4; ++i) {
        const long grow = m0 + wm * 64 + i * 16 + quad * 4;
#pragma unroll
        for (int j = 0; j < 2; ++j) {
            const long gcol = n0 + wn * 32 + j * 16 + l15;
#pragma unroll
            for (int r = 0; r < 4; ++r)
                C[(grow + r) * 256 + gcol] = acc[i][j][r];
        }
    }
}

// ---------------------------------------------------------------- node stats: g, dn, per-dd |y| max
__global__ __launch_bounds__(256) void node_stats1(
        const float* __restrict__ xw1, const float* __restrict__ a1,
        const float* __restrict__ a22, float* __restrict__ g_out,
        float* __restrict__ dn, unsigned int* __restrict__ ddmax) {
    __shared__ float Mx[4][260];
    const int t = threadIdx.x;
    const int n0 = blockIdx.x * 64;
    const int r = t >> 2, q = t & 3;
    const long n = n0 + r;
    const float* xp = xw1 + n * 256 + q * 64;
    float vals[64];
    float facc = 0.f, dacc = 0.f;
#pragma unroll
    for (int i = 0; i < 16; ++i) {
        f32x4 v  = *reinterpret_cast<const f32x4*>(xp + i * 4);
        f32x4 b1 = *reinterpret_cast<const f32x4*>(a1 + q * 64 + i * 4);
        f32x4 b2 = *reinterpret_cast<const f32x4*>(a22 + q * 64 + i * 4);
#pragma unroll
        for (int k = 0; k < 4; ++k) {
            float lv = leakyf(v[k]);
            facc += lv * b1[k];
            dacc += lv * b2[k];
            vals[i * 4 + k] = v[k];
        }
    }
    facc += __shfl_xor(facc, 1); facc += __shfl_xor(facc, 2);
    dacc += __shfl_xor(dacc, 1); dacc += __shfl_xor(dacc, 2);
    const float g = satexpf(facc);
    if (q == 0) { dn[n] = dacc; g_out[n] = g; }
    float lm[64];
#pragma unroll
    for (int i = 0; i < 64; ++i) lm[i] = fabsf(vals[i] * g);
#pragma unroll
    for (int m = 4; m < 64; m <<= 1)
#pragma unroll
        for (int i = 0; i < 64; ++i) lm[i] = fmaxf(lm[i], __shfl_xor(lm[i], m));
    float gm = g;
#pragma unroll
    for (int m = 1; m < 64; m <<= 1) gm = fmaxf(gm, __shfl_xor(gm, m));
    const int wv = t >> 6, lane = t & 63;
    if (lane < 4) {
#pragma unroll
        for (int i = 0; i < 64; ++i) Mx[wv][lane * 64 + i] = lm[i];
    }
    if (lane == 0) Mx[wv][256] = gm;
    __syncthreads();
    if (t < 256) {
        float m = fmaxf(fmaxf(Mx[0][t], Mx[1][t]), fmaxf(Mx[2][t], Mx[3][t]));
        atomicMax(&ddmax[t], __float_as_uint(m));
    }
    if (t == 0) {  // index 256 (g); block has only 256 threads
        float m = fmaxf(fmaxf(Mx[0][256], Mx[1][256]), fmaxf(Mx[2][256], Mx[3][256]));
        atomicMax(&ddmax[256], __float_as_uint(m));
    }
}

// ---------------------------------------------------------------- quantize y -> yQ i8 [576,16384]
__global__ __launch_bounds__(256) void quantize_y(
        const float* __restrict__ xw1, const float* __restrict__ g_in,
        const unsigned int* __restrict__ ddmax, char* __restrict__ yQ) {
    __shared__ unsigned int Qh[257][16];
    __shared__ unsigned int Ql[257][16];
    const int t = threadIdx.x;
    const int n0 = blockIdx.x * 64;
    const int dd0 = (t >> 4) * 16;
    const int w = t & 15;
    const int r4 = w * 4;
    float s[16];
#pragma unroll
    for (int i = 0; i < 16; ++i)
        s[i] = 32512.f / __uint_as_float(ddmax[dd0 + i]);
    const float sg = 32512.f / __uint_as_float(ddmax[256]);
    unsigned int bh[16], bl[16];
#pragma unroll
    for (int i = 0; i < 16; ++i) { bh[i] = 0u; bl[i] = 0u; }
    unsigned int gh = 0u, gl = 0u;
#pragma unroll
    for (int rr = 0; rr < 4; ++rr) {
        const long n = n0 + r4 + rr;
        const float gg = g_in[n];
        const float* xp = xw1 + n * 256 + dd0;
#pragma unroll
        for (int c = 0; c < 4; ++c) {
            f32x4 v = *reinterpret_cast<const f32x4*>(xp + c * 4);
#pragma unroll
            for (int k = 0; k < 4; ++k) {
                const int i = c * 4 + k;
                int qv = __float2int_rn(v[k] * gg * s[i]);
                qv = max(-32639, min(32639, qv));
                const int qh = (qv + 128) >> 8;
                const int ql = qv - (qh << 8);
                bh[i] |= ((unsigned int)(qh & 255)) << (8 * rr);
                bl[i] |= ((unsigned int)(ql & 255)) << (8 * rr);
            }
        }
        if (t < 16) {
            int qv = __float2int_rn(gg * sg);
            qv = max(-32639, min(32639, qv));
            const int qh = (qv + 128) >> 8;
            const int ql = qv - (qh << 8);
            gh |= ((unsigned int)(qh & 255)) << (8 * rr);
            gl |= ((unsigned int)(ql & 255)) << (8 * rr);
        }
    }
#pragma unroll
    for (int i = 0; i < 16; ++i) { Qh[dd0 + i][w] = bh[i]; Ql[dd0 + i][w] = bl[i]; }
    if (t < 16) { Qh[256][t] = gh; Ql[256][t] = gl; }
    __syncthreads();
#pragma unroll
    for (int it = 0; it < 2; ++it) {
        const int dd = it * 256 + t;
        if (dd < 288) {
#pragma unroll
            for (int s2 = 0; s2 < 4; ++s2) {
                uint4v vh, vl;
                if (dd < 257) {
                    vh = *reinterpret_cast<const uint4v*>(&Qh[dd][s2 * 4]);
                    vl = *reinterpret_cast<const uint4v*>(&Ql[dd][s2 * 4]);
                } else {
#pragma unroll
                    for (int k = 0; k < 4; ++k) { vh[k] = 0u; vl[k] = 0u; }
                }
                *reinterpret_cast<uint4v*>(yQ + (long)dd * 16384 + n0 + s2 * 16) = vh;
                *reinterpret_cast<uint4v*>(yQ + (long)(288 + dd) * 16384 + n0 + s2 * 16) = vl;
            }
        }
    }
}

// ---------------------------------------------------------------- C1 GEMM, i8 MFMA, A-fragments expanded IN REGISTERS
// BM=256 (j), BN=48 (dd), BK=128, z=8 (Ktile 2048), grid (16, 6, 8) = 768 blocks.
// No As LDS (was 36.9 KB): per lane, each A-fragment (16 rows x 64 K, 16 i8/lane)
// is 16 consecutive H-bits at offset ks*64+quad*16 of the row's 128-bit K-chunk,
// i.e. halfword (quad&1) of word (ks*2 + (quad>>1)) of one uint4 bit-load.
__global__ __launch_bounds__(256) void gemm_c1_bits(
        const unsigned int* __restrict__ HbitsT, const char* __restrict__ Bb,
        float* __restrict__ Cp) {
    __shared__ char Bsh[48][144];   // 6.9 KB
    __shared__ char Bsl[48][144];   // 6.9 KB
    const int t = threadIdx.x;
    const int wid = t >> 6, lane = t & 63;
    const int quad = lane >> 4, l15 = lane & 15;
    const long m0 = (long)blockIdx.x * 256;
    const long n0 = (long)blockIdx.y * 48;
    const long k0 = (long)blockIdx.z * 2048;
    float* Cz = Cp + (long)blockIdx.z * (4096L * 288);
    // this lane's 4 A-rows (j indices): m0 + wid*64 + i*16 + l15
    const unsigned int* bp[4];
#pragma unroll
    for (int i = 0; i < 4; ++i)
        bp[i] = HbitsT + (m0 + wid * 64 + i * 16 + l15) * 512 + (k0 >> 5);
    int4v acch[4][3], accl[4][3];
#pragma unroll
    for (int i = 0; i < 4; ++i)
#pragma unroll
        for (int j = 0; j < 3; ++j)
#pragma unroll
            for (int r = 0; r < 4; ++r) { acch[i][j][r] = 0; accl[i][j][r] = 0; }

    for (int kb = 0; kb < 2048; kb += 128) {
        // bit-loads for this K-chunk: one uint4 (128 bits) per row
        uint4v bv[4];
#pragma unroll
        for (int i = 0; i < 4; ++i)
            bv[i] = *reinterpret_cast<const uint4v*>(bp[i] + (kb >> 5));
        // B: 48 rows x 128 B x 2 planes = 768 x 16B chunks.
        // (round-6 bugfix kept: explicit compare, NOT `cid & 383`)
#pragma unroll
        for (int it = 0; it < 3; ++it) {
            const int cid = t + it * 256;
            const int idx = (cid < 384) ? cid : cid - 384;
            const int row = idx >> 3, seg = (idx & 7) * 16;
            char* dst = (cid >= 384) ? &Bsl[row][seg] : &Bsh[row][seg];
            const long srow = (cid >= 384) ? (288 + n0 + row) : (n0 + row);
            *reinterpret_cast<uint4v*>(dst) =
                *reinterpret_cast<const uint4v*>(Bb + srow * 16384 + k0 + kb + seg);
        }
        __syncthreads();
#pragma unroll
        for (int ks = 0; ks < 2; ++ks) {
            int4v af[4], bh[3], bl[3];
#pragma unroll
            for (int i = 0; i < 4; ++i) {
                const unsigned int u =
                    bv[i][ks * 2 + (quad >> 1)] >> ((quad & 1) * 16);
                uint4v e;
#pragma unroll
                for (int k = 0; k < 4; ++k) e[k] = bits4_to_bytes(u >> (4 * k));
                af[i] = __builtin_bit_cast(int4v, e);
            }
#pragma unroll
            for (int j = 0; j < 3; ++j) {
                bh[j] = *reinterpret_cast<const int4v*>(&Bsh[j * 16 + l15][ks * 64 + quad * 16]);
                bl[j] = *reinterpret_cast<const int4v*>(&Bsl[j * 16 + l15][ks * 64 + quad * 16]);
            }
#pragma unroll
            for (int i = 0; i < 4; ++i)
#pragma unroll
                for (int j = 0; j < 3; ++j) {
                    acch[i][j] = __builtin_amdgcn_mfma_i32_16x16x64_i8(af[i], bh[j], acch[i][j], 0, 0, 0);
                    accl[i][j] = __builtin_amdgcn_mfma_i32_16x16x64_i8(af[i], bl[j], accl[i][j], 0, 0, 0);
                }
        }
        __syncthreads();
    }
#pragma unroll
    for (int i = 0; i < 4; ++i) {
        const long grow = m0 + wid * 64 + i * 16 + quad * 4;
#pragma unroll
        for (int j = 0; j < 3; ++j) {
            const long gcol = n0 + j * 16 + l15;
#pragma unroll
            for (int r = 0; r < 4; ++r)
                Cz[(grow + r) * 288 + gcol] =
                    256.f * (float)acch[i][j][r] + (float)accl[i][j][r];
        }
    }
}

// ---------------------------------------------------------------- reduce split-K partials + reconstruct scale
__global__ __launch_bounds__(256) void reduce_C1(
        const float* __restrict__ C1p, const unsigned int* __restrict__ ddmax,
        float* __restrict__ C1) {
    const int i = blockIdx.x * 256 + threadIdx.x;   // < 4096*288
    const int dd = i % 288;
    float s = 0.f;
#pragma unroll
    for (int z = 0; z < 8; ++z) s += C1p[(long)z * 4096 * 288 + i];
    C1[i] = s * (__uint_as_float(ddmax[dd]) * (1.f / 32512.f));
}

// ---------------------------------------------------------------- G = f2@w2 split (+ GT bf16, c_j)
__global__ __launch_bounds__(256) void gemm_G(
        const float* __restrict__ C1, const short* __restrict__ w2Th,
        const short* __restrict__ w2Tl, const float* __restrict__ a21,
        short* __restrict__ GT, float* __restrict__ cat) {
    __shared__ short Ash[64][72];
    __shared__ short Asl[64][72];
    __shared__ short Bsh[64][72];
    __shared__ short Bsl[64][72];
    __shared__ float Gs[64][65];
    const int t = threadIdx.x;
    const int wid = t >> 6, lane = t & 63;
    const int wm = wid & 1, wn = wid >> 1;
    const int quad = lane >> 4, l15 = lane & 15;
    const long j0 = (long)blockIdx.x * 64;
    const long d0 = (long)blockIdx.y * 64;
    f32x4 acc[2][2];
#pragma unroll
    for (int i = 0; i < 2; ++i)
#pragma unroll
        for (int j = 0; j < 2; ++j)
#pragma unroll
            for (int r = 0; r < 4; ++r) acc[i][j][r] = 0.f;

    for (int kb = 0; kb < 256; kb += 64) {
#pragma unroll
        for (int it = 0; it < 2; ++it) {
            const int cid = t + it * 256;
            const int row = cid >> 3, c8 = (cid & 7) * 8;
            const float rd = fastrcp(C1[(j0 + row) * 288 + 256]);
            const float* ap = C1 + (j0 + row) * 288 + kb + c8;
            f32x4 v0 = *reinterpret_cast<const f32x4*>(ap);
            f32x4 v1 = *reinterpret_cast<const f32x4*>(ap + 4);
            short8 hi, lo;
#pragma unroll
            for (int k = 0; k < 4; ++k) {
                float f0 = leakyf(v0[k] * rd);
                float f1 = leakyf(v1[k] * rd);
                short h0 = f2b(f0); hi[k] = h0; lo[k] = f2b(f0 - b2f(h0));
                short h1 = f2b(f1); hi[4 + k] = h1; lo[4 + k] = f2b(f1 - b2f(h1));
            }
            *reinterpret_cast<short8*>(&Ash[row][c8]) = hi;
            *reinterpret_cast<short8*>(&Asl[row][c8]) = lo;
            *reinterpret_cast<short8*>(&Bsh[row][c8]) =
                *reinterpret_cast<const short8*>(w2Th + (d0 + row) * 256 + kb + c8);
            *reinterpret_cast<short8*>(&Bsl[row][c8]) =
                *reinterpret_cast<const short8*>(w2Tl + (d0 + row) * 256 + kb + c8);
        }
        __syncthreads();
#pragma unroll
        for (int ks = 0; ks < 2; ++ks) {
            short8 ah[2], al[2], bh[2], bl[2];
#pragma unroll
            for (int i = 0; i < 2; ++i) {
                ah[i] = *reinterpret_cast<const short8*>(&Ash[wm * 32 + i * 16 + l15][ks * 32 + quad * 8]);
                al[i] = *reinterpret_cast<const short8*>(&Asl[wm * 32 + i * 16 + l15][ks * 32 + quad * 8]);
            }
#pragma unroll
            for (int j = 0; j < 2; ++j) {
                bh[j] = *reinterpret_cast<const short8*>(&Bsh[wn * 32 + j * 16 + l15][ks * 32 + quad * 8]);
                bl[j] = *reinterpret_cast<const short8*>(&Bsl[wn * 32 + j * 16 + l15][ks * 32 + quad * 8]);
            }
#pragma unroll
            for (int i = 0; i < 2; ++i)
#pragma unroll
                for (int j = 0; j < 2; ++j) {
                    acc[i][j] = __builtin_amdgcn_mfma_f32_16x16x32_bf16(ah[i], bh[j], acc[i][j], 0, 0, 0);
                    acc[i][j] = __builtin_amdgcn_mfma_f32_16x16x32_bf16(ah[i], bl[j], acc[i][j], 0, 0, 0);
                    acc[i][j] = __builtin_amdgcn_mfma_f32_16x16x32_bf16(al[i], bh[j], acc[i][j], 0, 0, 0);
                }
        }
        __syncthreads();
    }
#pragma unroll
    for (int i = 0; i < 2; ++i)
#pragma unroll
        for (int j = 0; j < 2; ++j)
#pragma unroll
            for (int r = 0; r < 4; ++r)
                Gs[wm * 32 + i * 16 + quad * 4 + r][wn * 32 + j * 16 + l15] = acc[i][j][r];
    __syncthreads();
    {
        const int jl = t >> 2, q = t & 3;
        float cp = 0.f;
#pragma unroll
        for (int i = 0; i < 16; ++i) {
            const int d = q * 16 + i;
            cp += leakyf(Gs[jl][d]) * a21[d0 + d];
        }
        cp += __shfl_xor(cp, 1); cp += __shfl_xor(cp, 2);
        if (q == 0) atomicAdd(&cat[j0 + jl], cp);
    }
    {
        const int dl = t >> 2, q = t & 3;
        short8 pk0, pk1;
#pragma unroll
        for (int i = 0; i < 8; ++i) pk0[i] = f2b(Gs[q * 16 + i][dl]);
#pragma unroll
        for (int i = 0; i < 8; ++i) pk1[i] = f2b(Gs[q * 16 + 8 + i][dl]);
        short* gp = GT + (d0 + dl) * 4096 + j0 + q * 16;
        *reinterpret_cast<short8*>(gp) = pk0;
        *reinterpret_cast<short8*>(gp + 8) = pk1;
    }
}

// ---------------------------------------------------------------- FUSED edge weights + final GEMM, j-split
// BM=64, BN=256, BK=64, Ktile=1024 (z=4), 512 threads, grid (256,4) = 1024 blocks.
// Writes fp32 out-partials + rowsum-partials; combine_out applies leaky(/rowsum).
__global__ __launch_bounds__(512, 4) void fused_out_split(
        const unsigned int* __restrict__ Hbits, const float* __restrict__ cat,
        const float* __restrict__ dn, const short* __restrict__ GT,
        float* __restrict__ outP, float* __restrict__ rsP) {
    __shared__ short As[64][72];    // 9.2 KB
    __shared__ short Bs[256][72];   // 36.9 KB
    __shared__ float rsS[64][8];
    const int t = threadIdx.x;
    const int wid = t >> 6, lane = t & 63;
    const int wm = wid >> 2, wn = wid & 3;    // 2 m-groups x 4 n-groups
    const int quad = lane >> 4, l15 = lane & 15;
    const long m0 = (long)blockIdx.x * 64;
    const int z = blockIdx.y;
    const int kbase = z * 1024;
    const int r = t & 63, c8 = t >> 6;        // B-value role: row r, 8-col chunk c8
    const float drow = dn[m0 + r];
    const int bo = (c8 & 3) * 8;

    f32x4 acc[2][4];
#pragma unroll
    for (int i = 0; i < 2; ++i)
#pragma unroll
        for (int j = 0; j < 4; ++j)
#pragma unroll
            for (int x = 0; x < 4; ++x) acc[i][j][x] = 0.f;
    float racc = 0.f;

    for (int kk = 0; kk < 1024; kk += 64) {
        const int kb = kbase + kk;
        // stage GT tile 256x64 (2048 x 16B chunks over 512 threads)
#pragma unroll
        for (int it = 0; it < 4; ++it) {
            const int cid = t + it * 512;
            const int row = cid >> 3, cc = (cid & 7) * 8;
            *reinterpret_cast<short8*>(&Bs[row][cc]) =
                *reinterpret_cast<const short8*>(GT + row * 4096 + kb + cc);
        }
        // compute 8 B-values for (row r, cols kb + c8*8 .. +7)
        {
            const unsigned int w = Hbits[(m0 + r) * 128 + (kb >> 5) + (c8 >> 2)];
            f32x4 cv0 = *reinterpret_cast<const f32x4*>(cat + kb + c8 * 8);
            f32x4 cv1 = *reinterpret_cast<const f32x4*>(cat + kb + c8 * 8 + 4);
            short8 pk;
#pragma unroll
            for (int k = 0; k < 8; ++k) {
                const float cvk = (k < 4) ? cv0[k & 3] : cv1[k & 3];
                const float s = ((w >> (bo + k)) & 1u) ? satexpf(cvk + drow) : 0.f;
                const short sb = f2b(s);
                pk[k] = sb;
                racc += b2f(sb);
            }
            *reinterpret_cast<short8*>(&As[r][c8 * 8]) = pk;
        }
        __syncthreads();
#pragma unroll
        for (int ks = 0; ks < 2; ++ks) {
            short8 af[2], bf[4];
#pragma unroll
            for (int i = 0; i < 2; ++i)
                af[i] = *reinterpret_cast<const short8*>(
                        &As[wm * 32 + i * 16 + l15][ks * 32 + quad * 8]);
#pragma unroll
            for (int j = 0; j < 4; ++j)
                bf[j] = *reinterpret_cast<const short8*>(
                        &Bs[wn * 64 + j * 16 + l15][ks * 32 + quad * 8]);
#pragma unroll
            for (int i = 0; i < 2; ++i)
#pragma unroll
                for (int j = 0; j < 4; ++j)
                    acc[i][j] = __builtin_amdgcn_mfma_f32_16x16x32_bf16(
                            af[i], bf[j], acc[i][j], 0, 0, 0);
        }
        __syncthreads();
    }
    rsS[r][c8] = racc;
    __syncthreads();
    if (t < 64) {
        float s = 0.f;
#pragma unroll
        for (int i = 0; i < 8; ++i) s += rsS[t][i];
        rsP[z * 16384 + m0 + t] = s;
    }
    float* op = outP + (long)z * (16384L * 256);
#pragma unroll
    for (int i = 0; i < 2; ++i) {
#pragma unroll
        for (int j = 0; j < 4; ++j) {
            const long gcol = wn * 64 + j * 16 + l15;
#pragma unroll
            for (int x = 0; x < 4; ++x) {
                const long grow = m0 + wm * 32 + i * 16 + quad * 4 + x;
                op[grow * 256 + gcol] = acc[i][j][x];
            }
        }
    }
}

// ---------------------------------------------------------------- combine: out = leaky(sum_z outP / sum_z rsP)
__global__ __launch_bounds__(256) void combine_out(
        const float* __restrict__ outP, const float* __restrict__ rsP,
        float* __restrict__ out) {
    const long i = ((long)blockIdx.x * 256 + threadIdx.x) * 4;  // grid 4096
    const long n = i >> 8;
    f32x4 s = *reinterpret_cast<const f32x4*>(outP + i);
#pragma unroll
    for (int z = 1; z < 4; ++z) {
        f32x4 v = *reinterpret_cast<const f32x4*>(outP + (long)z * (16384L * 256) + i);
#pragma unroll
        for (int k = 0; k < 4; ++k) s[k] += v[k];
    }
    const float rinv = fastrcp(rsP[n] + rsP[16384 + n] + rsP[32768 + n] + rsP[49152 + n]);
    f32x4 o;
#pragma unroll
    for (int k = 0; k < 4; ++k) o[k] = leakyf(s[k] * rinv);
    *reinterpret_cast<f32x4*>(out + i) = o;
}

// ---------------------------------------------------------------- launch
extern "C" void kernel_launch(void* const* d_in, const int* in_sizes, int n_in,
                              void* d_out, int out_size, void* d_ws, size_t ws_size,
                              hipStream_t stream) {
    const float* x   = (const float*)d_in[0];
    const float* H   = (const float*)d_in[1];
    const float* w1  = (const float*)d_in[2];
    const float* w2  = (const float*)d_in[3];
    const float* a1  = (const float*)d_in[4];
    const float* a21 = (const float*)d_in[5];
    const float* a22 = (const float*)d_in[6];
    float* out = (float*)d_out;
    char* ws = (char*)d_ws;

    // region0: xw1 fp32 (16.8MB) then C1p fp32 [8][4096][288] (37.75MB) -- sequential reuse
    float* xw1   = (float*)(ws + 0);
    float* C1p   = (float*)(ws + 0);
    char*  yQ    = (char*)(ws + 67108864);                // [576,16384] i8 (9.44MB)
    float* dn    = (float*)(ws + 76546048);               // [16384]
    float* g     = (float*)(ws + 76611584);               // [16384]
    unsigned int* ddmax = (unsigned int*)(ws + 76677120); // [288]
    short* w1Th  = (short*)(ws + 76681216);
    short* w1Tl  = (short*)(ws + 76812288);
    short* w2Th  = (short*)(ws + 76943360);
    short* w2Tl  = (short*)(ws + 77074432);
    float* C1    = (float*)(ws + 77205504);               // [4096,288]
    short* GT    = (short*)(ws + 81924096);               // [256,4096] bf16
    float* cat   = (float*)(ws + 84021248);               // [4096]
    unsigned int* Hbits  = (unsigned int*)(ws + 84037632);// [16384,128] (8MB)
    unsigned int* HbitsT = (unsigned int*)(ws + 92426240);// [4096,512]  (8MB)
    float* outP  = (float*)(ws + 134217728);              // [4][16384,256] (67.1MB)
    float* rsP   = (float*)(ws + 201326592);              // [4][16384]

    transpose_split2<<<dim3(4, 4, 2), 256, 0, stream>>>(
            w1, w1Th, w1Tl, w2, w2Th, w2Tl);
    transposeH_pack<<<dim3(256, 64), 256, 0, stream>>>(H, Hbits, HbitsT, ddmax, cat);

    gemm_xw1<<<dim3(128, 4), 256, 0, stream>>>(x, w1Th, w1Tl, xw1);
    node_stats1<<<dim3(256), 256, 0, stream>>>(xw1, a1, a22, g, dn, ddmax);
    quantize_y<<<dim3(256), 256, 0, stream>>>(xw1, g, ddmax, yQ);

    gemm_c1_bits<<<dim3(16, 6, 8), 256, 0, stream>>>(HbitsT, yQ, C1p);
    reduce_C1<<<dim3(4608), 256, 0, stream>>>(C1p, ddmax, C1);

    gemm_G<<<dim3(64, 4), 256, 0, stream>>>(C1, w2Th, w2Tl, a21, GT, cat);

    fused_out_split<<<dim3(256, 4), 512, 0, stream>>>(Hbits, cat, dn, GT, outP, rsP);
    combine_out<<<dim3(4096), 256, 0, stream>>>(outP, rsP, out);
}